// Round 1
// baseline (3750.770 us; speedup 1.0000x reference)
//
#include <hip/hip_runtime.h>
#include <hip/hip_bf16.h>
#include <math.h>

#define NN 100000
#define NE 1600000
#define DIM 128
#define NG 64
#define EPSBN 1e-5f

// ---------------- degree / CSR build ----------------
__global__ void k_deg_hist(const int* __restrict__ ei, int* __restrict__ deg) {
    int e = blockIdx.x * blockDim.x + threadIdx.x;
    if (e < NE) atomicAdd(&deg[ei[NE + e]], 1);
}

__global__ void k_inv_deg(const int* __restrict__ deg, float* __restrict__ inv_deg) {
    int i = blockIdx.x * blockDim.x + threadIdx.x;
    if (i < NN) {
        int d = deg[i];
        inv_deg[i] = 1.0f / (float)(d > 1 ? d : 1);
    }
}

#define SCAN_B 256
__global__ void k_scan1(const int* __restrict__ deg, int* __restrict__ row_start,
                        int* __restrict__ bsum) {
    __shared__ int s[SCAN_B];
    int t = threadIdx.x;
    int i = blockIdx.x * SCAN_B + t;
    int v = (i < NN) ? deg[i] : 0;
    s[t] = v;
    for (int off = 1; off < SCAN_B; off <<= 1) {
        __syncthreads();
        int x = (t >= off) ? s[t - off] : 0;
        __syncthreads();
        s[t] += x;
    }
    if (i < NN) row_start[i + 1] = s[t];           // inclusive within block
    if (t == SCAN_B - 1) bsum[blockIdx.x] = s[t];  // block total
}

__global__ void k_scan2(int* __restrict__ bsum, int nb) {
    __shared__ int s[512];
    int t = threadIdx.x;
    int v = (t < nb) ? bsum[t] : 0;
    s[t] = v;
    for (int off = 1; off < 512; off <<= 1) {
        __syncthreads();
        int x = (t >= off) ? s[t - off] : 0;
        __syncthreads();
        s[t] += x;
    }
    if (t < nb) bsum[t] = s[t] - v;  // exclusive scan of block totals
}

__global__ void k_scan3(int* __restrict__ row_start, const int* __restrict__ bsum) {
    int i = blockIdx.x * blockDim.x + threadIdx.x;
    if (i < NN) row_start[i + 1] += bsum[i / SCAN_B];
    if (i == 0) row_start[0] = 0;
}

__global__ void k_copy_cursor(const int* __restrict__ row_start, int* __restrict__ cursor) {
    int i = blockIdx.x * blockDim.x + threadIdx.x;
    if (i < NN) cursor[i] = row_start[i];
}

__global__ void k_sort(const int* __restrict__ ei, int* __restrict__ cursor,
                       int* __restrict__ sorted_src) {
    int e = blockIdx.x * blockDim.x + threadIdx.x;
    if (e < NE) {
        int s = ei[e];
        int d = ei[NE + e];
        int pos = atomicAdd(&cursor[d], 1);
        sorted_src[pos] = s;
    }
}

// ---------------- mean aggregation: one wave per dst node ----------------
__global__ void k_aggregate(const float* __restrict__ h, const int* __restrict__ row_start,
                            const int* __restrict__ sorted_src, const float* __restrict__ inv_deg,
                            float* __restrict__ agg) {
    int wid = (blockIdx.x * blockDim.x + threadIdx.x) >> 6;
    int lane = threadIdx.x & 63;
    if (wid >= NN) return;
    int beg = row_start[wid], end = row_start[wid + 1];
    float ax = 0.f, ay = 0.f;
    for (int e = beg; e < end; ++e) {
        int s = sorted_src[e];
        float2 v = *reinterpret_cast<const float2*>(&h[s * DIM + lane * 2]);
        ax += v.x; ay += v.y;
    }
    float sc = inv_deg[wid];
    float2 o; o.x = ax * sc; o.y = ay * sc;
    *reinterpret_cast<float2*>(&agg[wid * DIM + lane * 2]) = o;
}

// ---------------- fused conv GEMM: C = A1@W1 + A2@W2 + bias (optional ReLU) ----
// A1,A2: [NN,128]; W1,W2: [128,128]; C: [NN,128]
#define BM 128
#define BKK 32
template <bool RELU>
__global__ __launch_bounds__(256) void k_gemm(const float* __restrict__ A1,
                                              const float* __restrict__ A2,
                                              const float* __restrict__ W1,
                                              const float* __restrict__ W2,
                                              const float* __restrict__ bias,
                                              float* __restrict__ C) {
    __shared__ float As[BKK][BM + 4];  // [k][r], stride 132 keeps 16B alignment
    __shared__ float Ws[BKK][DIM];     // [k][c]
    int t = threadIdx.x;
    int tx = t & 15;       // col group 0..15
    int ty = t >> 4;       // row group 0..15
    int r0 = blockIdx.x * BM;

    float acc[8][8];
#pragma unroll
    for (int i = 0; i < 8; i++)
#pragma unroll
        for (int j = 0; j < 8; j++) acc[i][j] = 0.f;

    for (int kk = 0; kk < 256; kk += BKK) {
        const float* A = (kk < 128) ? A1 : A2;
        const float* W = (kk < 128) ? W1 : W2;
        int kbase = kk & 127;
        // A tile: 128 rows x 32 k  (transpose into As[k][r])
        {
            int k4 = (t & 7) * 4;
            int rr = t >> 3;  // 0..31
#pragma unroll
            for (int i = 0; i < 4; i++) {
                int r = rr + i * 32;
                int gr = r0 + r;
                float4 v = make_float4(0.f, 0.f, 0.f, 0.f);
                if (gr < NN) v = *reinterpret_cast<const float4*>(&A[gr * DIM + kbase + k4]);
                As[k4 + 0][r] = v.x; As[k4 + 1][r] = v.y;
                As[k4 + 2][r] = v.z; As[k4 + 3][r] = v.w;
            }
            // W tile: 32 k x 128 c
            int c4 = (t & 31) * 4;
            int kR = t >> 5;  // 0..7
#pragma unroll
            for (int i = 0; i < 4; i++) {
                int k = kR + i * 8;
                *reinterpret_cast<float4*>(&Ws[k][c4]) =
                    *reinterpret_cast<const float4*>(&W[(kbase + k) * DIM + c4]);
            }
        }
        __syncthreads();
#pragma unroll
        for (int k = 0; k < BKK; k++) {
            float a[8], b[8];
            *(float4*)&a[0] = *(const float4*)&As[k][ty * 8];
            *(float4*)&a[4] = *(const float4*)&As[k][ty * 8 + 4];
            *(float4*)&b[0] = *(const float4*)&Ws[k][tx * 8];
            *(float4*)&b[4] = *(const float4*)&Ws[k][tx * 8 + 4];
#pragma unroll
            for (int i = 0; i < 8; i++)
#pragma unroll
                for (int j = 0; j < 8; j++) acc[i][j] += a[i] * b[j];
        }
        __syncthreads();
    }
    // epilogue
#pragma unroll
    for (int i = 0; i < 8; i++) {
        int gr = r0 + ty * 8 + i;
        if (gr < NN) {
#pragma unroll
            for (int j = 0; j < 8; j += 4) {
                float4 v;
                v.x = acc[i][j + 0] + bias[tx * 8 + j + 0];
                v.y = acc[i][j + 1] + bias[tx * 8 + j + 1];
                v.z = acc[i][j + 2] + bias[tx * 8 + j + 2];
                v.w = acc[i][j + 3] + bias[tx * 8 + j + 3];
                if (RELU) {
                    v.x = fmaxf(v.x, 0.f); v.y = fmaxf(v.y, 0.f);
                    v.z = fmaxf(v.z, 0.f); v.w = fmaxf(v.w, 0.f);
                }
                *reinterpret_cast<float4*>(&C[gr * DIM + tx * 8 + j]) = v;
            }
        }
    }
}

// ---------------- BatchNorm ----------------
__global__ void k_bn_stats(const float* __restrict__ h, float* __restrict__ colsum,
                           float* __restrict__ colsumsq) {
    int c = threadIdx.x;  // 128 threads
    int r0 = blockIdx.x * 128;
    int rend = min(r0 + 128, NN);
    float s = 0.f, s2 = 0.f;
    for (int r = r0; r < rend; ++r) {
        float v = h[r * DIM + c];
        s += v; s2 += v * v;
    }
    atomicAdd(&colsum[c], s);
    atomicAdd(&colsumsq[c], s2);
}

__global__ void k_bn_finalize(const float* __restrict__ colsum, const float* __restrict__ colsumsq,
                              const float* __restrict__ gamma, const float* __restrict__ beta,
                              float* __restrict__ scale, float* __restrict__ shift) {
    int c = threadIdx.x;
    float mu = colsum[c] * (1.0f / NN);
    float var = colsumsq[c] * (1.0f / NN) - mu * mu;
    float rstd = rsqrtf(var + EPSBN);
    float sc = rstd * gamma[c];
    scale[c] = sc;
    shift[c] = beta[c] - mu * sc;
}

__global__ void k_bn_apply(float* __restrict__ h, const float* __restrict__ scale,
                           const float* __restrict__ shift) {
    int i = blockIdx.x * blockDim.x + threadIdx.x;  // over NN*DIM/4
    int base = i * 4;
    if (base < NN * DIM) {
        float4 v = *reinterpret_cast<const float4*>(&h[base]);
        int c = base & 127;
        v.x = fmaxf(v.x * scale[c + 0] + shift[c + 0], 0.f);
        v.y = fmaxf(v.y * scale[c + 1] + shift[c + 1], 0.f);
        v.z = fmaxf(v.z * scale[c + 2] + shift[c + 2], 0.f);
        v.w = fmaxf(v.w * scale[c + 3] + shift[c + 3], 0.f);
        *reinterpret_cast<float4*>(&h[base]) = v;
    }
}

// ---------------- pooling ----------------
__global__ void k_cnt_hist(const int* __restrict__ batch, int* __restrict__ cnt) {
    int i = blockIdx.x * blockDim.x + threadIdx.x;
    if (i < NN) atomicAdd(&cnt[batch[i]], 1);
}

__global__ void k_pool(const float* __restrict__ h, const int* __restrict__ batch,
                       float* __restrict__ pooled) {
    int wid = (blockIdx.x * blockDim.x + threadIdx.x) >> 6;
    int lane = threadIdx.x & 63;
    if (wid >= NN) return;
    int g = batch[wid];
    float2 v = *reinterpret_cast<const float2*>(&h[wid * DIM + lane * 2]);
    atomicAdd(&pooled[g * 256 + lane * 2 + 0], v.x);
    atomicAdd(&pooled[g * 256 + lane * 2 + 1], v.y);
    // post-ReLU values are >= 0 -> int compare == float compare; pooled init 0
    atomicMax((int*)&pooled[g * 256 + 128 + lane * 2 + 0], __float_as_int(v.x));
    atomicMax((int*)&pooled[g * 256 + 128 + lane * 2 + 1], __float_as_int(v.y));
}

// ---------------- classifier MLP: one block per graph ----------------
__global__ void k_mlp(const float* __restrict__ pooled, const int* __restrict__ cnt,
                      const float* __restrict__ W1, const float* __restrict__ b1,
                      const float* __restrict__ W2, const float* __restrict__ b2,
                      const float* __restrict__ W3, const float* __restrict__ b3,
                      float* __restrict__ out) {
    __shared__ float g[256], y1[128], y2[64];
    int gi = blockIdx.x;
    int t = threadIdx.x;  // 128 threads
    float inv = 1.0f / fmaxf((float)cnt[gi], 1.0f);
    g[t] = pooled[gi * 256 + t] * inv;           // mean part
    g[128 + t] = pooled[gi * 256 + 128 + t];     // max part
    __syncthreads();
    float a = b1[t];
    for (int k = 0; k < 256; k++) a += g[k] * W1[k * 128 + t];
    y1[t] = fmaxf(a, 0.f);
    __syncthreads();
    if (t < 64) {
        float a2 = b2[t];
        for (int k = 0; k < 128; k++) a2 += y1[k] * W2[k * 64 + t];
        y2[t] = fmaxf(a2, 0.f);
    }
    __syncthreads();
    if (t < 64) {
        float p = y2[t] * W3[t];
#pragma unroll
        for (int off = 32; off; off >>= 1) p += __shfl_down(p, off);
        if (t == 0) out[gi] = p + b3[0];
    }
}

extern "C" void kernel_launch(void* const* d_in, const int* in_sizes, int n_in,
                              void* d_out, int out_size, void* d_ws, size_t ws_size,
                              hipStream_t stream) {
    const float* x     = (const float*)d_in[0];
    const int*   ei    = (const int*)d_in[1];     // [2,E]
    const int*   batch = (const int*)d_in[2];     // [N]
    const float* Wl    = (const float*)d_in[3];   // [8,128,128]
    const float* bl    = (const float*)d_in[4];   // [8,128]
    const float* Wr    = (const float*)d_in[5];   // [8,128,128]
    const float* gamma = (const float*)d_in[6];   // [4,128]
    const float* beta  = (const float*)d_in[7];   // [4,128]
    const float* W1    = (const float*)d_in[8];   // [256,128]
    const float* b1    = (const float*)d_in[9];
    const float* W2    = (const float*)d_in[10];  // [128,64]
    const float* b2    = (const float*)d_in[11];
    const float* W3    = (const float*)d_in[12];  // [64,1]
    const float* b3    = (const float*)d_in[13];
    float* out = (float*)d_out;

    // workspace carve-up (256B aligned)
    char* p = (char*)d_ws;
    size_t off = 0;
    auto alloc = [&](size_t bytes) -> void* {
        void* r = p + off;
        off += (bytes + 255) & ~(size_t)255;
        return r;
    };
    float* hA        = (float*)alloc((size_t)NN * DIM * 4);
    float* hB        = (float*)alloc((size_t)NN * DIM * 4);
    float* agg       = (float*)alloc((size_t)NN * DIM * 4);
    int*   deg       = (int*)alloc(NN * 4);
    float* inv_deg   = (float*)alloc(NN * 4);
    int*   row_start = (int*)alloc((NN + 1) * 4);
    int*   cursor    = (int*)alloc(NN * 4);
    int*   bsum      = (int*)alloc(512 * 4);
    int*   ssrc      = (int*)alloc((size_t)NE * 4);
    float* colstats  = (float*)alloc(256 * 4);   // colsum[128] | colsumsq[128]
    float* scaleshift= (float*)alloc(256 * 4);   // scale[128]  | shift[128]
    float* pooled    = (float*)alloc(NG * 256 * 4);
    int*   cnt       = (int*)alloc(NG * 4);

    const int nbN = (NN + 255) / 256;   // 391
    const int nbE = (NE + 255) / 256;   // 6250

    // CSR build
    hipMemsetAsync(deg, 0, NN * 4, stream);
    k_deg_hist<<<nbE, 256, 0, stream>>>(ei, deg);
    k_inv_deg<<<nbN, 256, 0, stream>>>(deg, inv_deg);
    k_scan1<<<nbN, 256, 0, stream>>>(deg, row_start, bsum);
    k_scan2<<<1, 512, 0, stream>>>(bsum, nbN);
    k_scan3<<<nbN, 256, 0, stream>>>(row_start, bsum);
    k_copy_cursor<<<nbN, 256, 0, stream>>>(row_start, cursor);
    k_sort<<<nbE, 256, 0, stream>>>(ei, cursor, ssrc);

    const int aggGrid  = (NN + 3) / 4;          // 4 waves/block, wave per node
    const int gemmGrid = (NN + BM - 1) / BM;    // 782
    const int bnApplyGrid = (NN * DIM / 4 + 255) / 256;

    const float* h_in = x;
    for (int b = 0; b < 4; b++) {
        int c0 = 2 * b, c1 = 2 * b + 1;
        k_aggregate<<<aggGrid, 256, 0, stream>>>(h_in, row_start, ssrc, inv_deg, agg);
        k_gemm<true><<<gemmGrid, 256, 0, stream>>>(agg, h_in, Wl + c0 * DIM * DIM,
                                                   Wr + c0 * DIM * DIM, bl + c0 * DIM, hA);
        k_aggregate<<<aggGrid, 256, 0, stream>>>(hA, row_start, ssrc, inv_deg, agg);
        k_gemm<false><<<gemmGrid, 256, 0, stream>>>(agg, hA, Wl + c1 * DIM * DIM,
                                                    Wr + c1 * DIM * DIM, bl + c1 * DIM, hB);
        hipMemsetAsync(colstats, 0, 256 * 4, stream);
        k_bn_stats<<<gemmGrid, 128, 0, stream>>>(hB, colstats, colstats + 128);
        k_bn_finalize<<<1, 128, 0, stream>>>(colstats, colstats + 128, gamma + b * DIM,
                                             beta + b * DIM, scaleshift, scaleshift + 128);
        k_bn_apply<<<bnApplyGrid, 256, 0, stream>>>(hB, scaleshift, scaleshift + 128);
        h_in = hB;
    }

    // pooling + classifier
    hipMemsetAsync(pooled, 0, NG * 256 * 4, stream);
    hipMemsetAsync(cnt, 0, NG * 4, stream);
    k_cnt_hist<<<nbN, 256, 0, stream>>>(batch, cnt);
    k_pool<<<aggGrid, 256, 0, stream>>>(hB, batch, pooled);
    k_mlp<<<NG, 128, 0, stream>>>(pooled, cnt, W1, b1, W2, b2, W3, b3, out);
}

// Round 2
// 2247.111 us; speedup vs baseline: 1.6692x; 1.6692x over previous
//
#include <hip/hip_runtime.h>
#include <hip/hip_bf16.h>
#include <math.h>

#define NN 100000
#define NE 1600000
#define DIM 128
#define NG 64
#define EPSBN 1e-5f
#define NBLK 782  // (NN+127)/128

typedef unsigned int u32;
typedef unsigned short u16;
typedef __attribute__((ext_vector_type(8))) short bf8_t;   // 8 x bf16
typedef __attribute__((ext_vector_type(4))) float f4_t;    // 4 x f32
typedef __attribute__((ext_vector_type(4))) unsigned short u16x4;
#define MFMA(a, b, c) __builtin_amdgcn_mfma_f32_16x16x32_bf16((a), (b), (c), 0, 0, 0)

__device__ __forceinline__ u16 f2bf(float f) {
    u32 u = __float_as_uint(f);
    u32 r = u + 0x7FFFu + ((u >> 16) & 1u);   // round-to-nearest-even
    return (u16)(r >> 16);
}
__device__ __forceinline__ float bf2f(u16 h) { return __uint_as_float(((u32)h) << 16); }

// ---------------- degree / CSR build ----------------
__global__ void k_deg_hist(const int* __restrict__ ei, int* __restrict__ deg) {
    int e = blockIdx.x * blockDim.x + threadIdx.x;
    if (e < NE) atomicAdd(&deg[ei[NE + e]], 1);
}

__global__ void k_inv_deg(const int* __restrict__ deg, float* __restrict__ inv_deg) {
    int i = blockIdx.x * blockDim.x + threadIdx.x;
    if (i < NN) {
        int d = deg[i];
        inv_deg[i] = 1.0f / (float)(d > 1 ? d : 1);
    }
}

#define SCAN_B 256
__global__ void k_scan1(const int* __restrict__ deg, int* __restrict__ row_start,
                        int* __restrict__ bsum) {
    __shared__ int s[SCAN_B];
    int t = threadIdx.x;
    int i = blockIdx.x * SCAN_B + t;
    int v = (i < NN) ? deg[i] : 0;
    s[t] = v;
    for (int off = 1; off < SCAN_B; off <<= 1) {
        __syncthreads();
        int x = (t >= off) ? s[t - off] : 0;
        __syncthreads();
        s[t] += x;
    }
    if (i < NN) row_start[i + 1] = s[t];
    if (t == SCAN_B - 1) bsum[blockIdx.x] = s[t];
}

__global__ void k_scan2(int* __restrict__ bsum, int nb) {
    __shared__ int s[512];
    int t = threadIdx.x;
    int v = (t < nb) ? bsum[t] : 0;
    s[t] = v;
    for (int off = 1; off < 512; off <<= 1) {
        __syncthreads();
        int x = (t >= off) ? s[t - off] : 0;
        __syncthreads();
        s[t] += x;
    }
    if (t < nb) bsum[t] = s[t] - v;
}

__global__ void k_scan3(int* __restrict__ row_start, const int* __restrict__ bsum) {
    int i = blockIdx.x * blockDim.x + threadIdx.x;
    if (i < NN) row_start[i + 1] += bsum[i / SCAN_B];
    if (i == 0) row_start[0] = 0;
}

__global__ void k_copy_cursor(const int* __restrict__ row_start, int* __restrict__ cursor) {
    int i = blockIdx.x * blockDim.x + threadIdx.x;
    if (i < NN) cursor[i] = row_start[i];
}

__global__ void k_sort(const int* __restrict__ ei, int* __restrict__ cursor,
                       int* __restrict__ sorted_src) {
    int e = blockIdx.x * blockDim.x + threadIdx.x;
    if (e < NE) {
        int s = ei[e];
        int d = ei[NE + e];
        int pos = atomicAdd(&cursor[d], 1);
        sorted_src[pos] = s;
    }
}

// graph ranges via binary search (batch is sorted)
__global__ void k_bounds(const int* __restrict__ batch, int* __restrict__ gs) {
    int g = threadIdx.x;
    if (g > NG) return;
    int lo = 0, hi = NN;
    while (lo < hi) {
        int mid = (lo + hi) >> 1;
        if (batch[mid] < g) lo = mid + 1; else hi = mid;
    }
    gs[g] = lo;  // first index with batch >= g; gs[NG] = NN
}

// ---------------- fp32 x -> split bf16 (hi, lo) ----------------
__global__ void k_split_x(const float* __restrict__ x, u16* __restrict__ Xh,
                          u16* __restrict__ Xl) {
    int idx = blockIdx.x * 256 + threadIdx.x;  // over NN*DIM/4
    int base = idx * 4;
    float4 v = *reinterpret_cast<const float4*>(&x[base]);
    u16x4 hi, lo;
    float vv[4] = {v.x, v.y, v.z, v.w};
#pragma unroll
    for (int j = 0; j < 4; j++) {
        u16 h = f2bf(vv[j]);
        hi[j] = h;
        lo[j] = f2bf(vv[j] - bf2f(h));
    }
    *reinterpret_cast<u16x4*>(&Xh[base]) = hi;
    *reinterpret_cast<u16x4*>(&Xl[base]) = lo;
}

// ---------------- weight prep: transpose+stack+split ----------------
// Wt[conv][col][k], k<128 -> Wl[conv][k][col], k>=128 -> Wr[conv][k-128][col]
__global__ void k_prep_w(const float* __restrict__ Wl, const float* __restrict__ Wr,
                         u16* __restrict__ Wth, u16* __restrict__ Wtl) {
    int idx = blockIdx.x * 256 + threadIdx.x;  // 8*128*256
    int k = idx & 255;
    int col = (idx >> 8) & 127;
    int c = idx >> 15;
    float v = (k < 128) ? Wl[(c * 128 + k) * 128 + col] : Wr[(c * 128 + (k - 128)) * 128 + col];
    u16 h = f2bf(v);
    Wth[idx] = h;
    Wtl[idx] = f2bf(v - bf2f(h));
}

// ---------------- mean aggregation: one wave per dst node, split in/out -------
__global__ void k_aggregate(const u16* __restrict__ Hh, const u16* __restrict__ Hl,
                            const int* __restrict__ row_start, const int* __restrict__ ssrc,
                            const float* __restrict__ inv_deg,
                            u16* __restrict__ Ah, u16* __restrict__ Al) {
    int wid = blockIdx.x * 4 + (threadIdx.x >> 6);
    int lane = threadIdx.x & 63;
    if (wid >= NN) return;
    int beg = row_start[wid], end = row_start[wid + 1];
    float a0 = 0.f, a1 = 0.f;
    for (int base = beg; base < end; base += 64) {
        int nv = end - base;
        int idx = base + (lane < nv ? lane : 0);
        int sv = ssrc[idx];
        int n = nv < 64 ? nv : 64;
        for (int j = 0; j < n; ++j) {
            int s = __shfl(sv, j);
            u32 h2 = *reinterpret_cast<const u32*>(Hh + s * DIM + lane * 2);
            u32 l2 = *reinterpret_cast<const u32*>(Hl + s * DIM + lane * 2);
            a0 += __uint_as_float(h2 << 16) + __uint_as_float(l2 << 16);
            a1 += __uint_as_float(h2 & 0xFFFF0000u) + __uint_as_float(l2 & 0xFFFF0000u);
        }
    }
    float sc = inv_deg[wid];
    a0 *= sc; a1 *= sc;
    u16 h0 = f2bf(a0), h1 = f2bf(a1);
    u16 l0 = f2bf(a0 - bf2f(h0)), l1 = f2bf(a1 - bf2f(h1));
    *reinterpret_cast<u32*>(Ah + wid * DIM + lane * 2) = (u32)h0 | ((u32)h1 << 16);
    *reinterpret_cast<u32*>(Al + wid * DIM + lane * 2) = (u32)l0 | ((u32)l1 << 16);
}

// ---------------- fused conv GEMM (MFMA, split-bf16 = fp32-accurate) ---------
// C[N,128] = A1@W[0:128] + A2@W[128:256] + bias ; A* split hi/lo; W pre-transposed
// block = 256 thr = 4 waves, each wave: 32 rows x 128 cols = 2x8 frags 16x16
template <bool RELU, bool STATS>
__global__ __launch_bounds__(256) void k_gemm(
    const u16* __restrict__ A1h, const u16* __restrict__ A1l,
    const u16* __restrict__ A2h, const u16* __restrict__ A2l,
    const u16* __restrict__ Wth, const u16* __restrict__ Wtl,
    const float* __restrict__ bias,
    u16* __restrict__ Oh, u16* __restrict__ Ol,
    float* __restrict__ partials) {
    __shared__ float cs[128], cq[128];
    int t = threadIdx.x;
    if (STATS) {
        if (t < 128) { cs[t] = 0.f; cq[t] = 0.f; }
        __syncthreads();
    }
    int w = t >> 6, l = t & 63;
    int rl = l & 15, kg = l >> 4;
    int rbase = blockIdx.x * 128 + w * 32;
    int row0 = rbase + rl, row1 = rbase + 16 + rl;
    int row0c = min(row0, NN - 1), row1c = min(row1, NN - 1);

    f4_t acc[2][8];
#pragma unroll
    for (int i = 0; i < 2; i++)
#pragma unroll
        for (int j = 0; j < 8; j++) acc[i][j] = (f4_t){0.f, 0.f, 0.f, 0.f};

#pragma unroll
    for (int ks = 0; ks < 4; ++ks) {  // K half 1: A1 (agg)
        int k0 = ks * 32 + kg * 8;
        bf8_t a0h = *reinterpret_cast<const bf8_t*>(A1h + row0c * DIM + k0);
        bf8_t a0l = *reinterpret_cast<const bf8_t*>(A1l + row0c * DIM + k0);
        bf8_t a1h = *reinterpret_cast<const bf8_t*>(A1h + row1c * DIM + k0);
        bf8_t a1l = *reinterpret_cast<const bf8_t*>(A1l + row1c * DIM + k0);
#pragma unroll
        for (int cf = 0; cf < 8; ++cf) {
            int wo = (cf * 16 + rl) * 256 + k0;
            bf8_t bh = *reinterpret_cast<const bf8_t*>(Wth + wo);
            bf8_t bl_ = *reinterpret_cast<const bf8_t*>(Wtl + wo);
            acc[0][cf] = MFMA(a0h, bh, acc[0][cf]);
            acc[0][cf] = MFMA(a0h, bl_, acc[0][cf]);
            acc[0][cf] = MFMA(a0l, bh, acc[0][cf]);
            acc[1][cf] = MFMA(a1h, bh, acc[1][cf]);
            acc[1][cf] = MFMA(a1h, bl_, acc[1][cf]);
            acc[1][cf] = MFMA(a1l, bh, acc[1][cf]);
        }
    }
#pragma unroll
    for (int ks = 0; ks < 4; ++ks) {  // K half 2: A2 (h)
        int k0 = ks * 32 + kg * 8;
        bf8_t a0h = *reinterpret_cast<const bf8_t*>(A2h + row0c * DIM + k0);
        bf8_t a0l = *reinterpret_cast<const bf8_t*>(A2l + row0c * DIM + k0);
        bf8_t a1h = *reinterpret_cast<const bf8_t*>(A2h + row1c * DIM + k0);
        bf8_t a1l = *reinterpret_cast<const bf8_t*>(A2l + row1c * DIM + k0);
#pragma unroll
        for (int cf = 0; cf < 8; ++cf) {
            int wo = (cf * 16 + rl) * 256 + 128 + k0;
            bf8_t bh = *reinterpret_cast<const bf8_t*>(Wth + wo);
            bf8_t bl_ = *reinterpret_cast<const bf8_t*>(Wtl + wo);
            acc[0][cf] = MFMA(a0h, bh, acc[0][cf]);
            acc[0][cf] = MFMA(a0h, bl_, acc[0][cf]);
            acc[0][cf] = MFMA(a0l, bh, acc[0][cf]);
            acc[1][cf] = MFMA(a1h, bh, acc[1][cf]);
            acc[1][cf] = MFMA(a1h, bl_, acc[1][cf]);
            acc[1][cf] = MFMA(a1l, bh, acc[1][cf]);
        }
    }

    // epilogue: C/D layout col = lane&15, row = (lane>>4)*4 + i  [verified m89]
#pragma unroll
    for (int rf = 0; rf < 2; ++rf) {
        int rb = rbase + rf * 16 + kg * 4;
#pragma unroll
        for (int cf = 0; cf < 8; ++cf) {
            int col = cf * 16 + rl;
            float bv = bias[col];
            float s = 0.f, q = 0.f;
#pragma unroll
            for (int i = 0; i < 4; ++i) {
                int row = rb + i;
                float v = acc[rf][cf][i] + bv;
                if (RELU) v = fmaxf(v, 0.f);
                if (row < NN) {
                    u16 hi = f2bf(v);
                    Oh[row * DIM + col] = hi;
                    Ol[row * DIM + col] = f2bf(v - bf2f(hi));
                    if (STATS) { s += v; q += v * v; }
                }
            }
            if (STATS) {
                s += __shfl_xor(s, 16); s += __shfl_xor(s, 32);
                q += __shfl_xor(q, 16); q += __shfl_xor(q, 32);
                if (l < 16) {
                    atomicAdd(&cs[col], s);
                    atomicAdd(&cq[col], q);
                }
            }
        }
    }
    if (STATS) {
        __syncthreads();
        partials[blockIdx.x * 256 + t] = (t < 128) ? cs[t] : cq[t - 128];
    }
}

// ---------------- BN: reduce partials -> scale/shift ----------------
__global__ void k_bn_reduce(const float* __restrict__ partials, const float* __restrict__ gamma,
                            const float* __restrict__ beta, float* __restrict__ scaleshift) {
    __shared__ float sm[256];
    int t = threadIdx.x;
    float s = 0.f;
    for (int b = 0; b < NBLK; ++b) s += partials[b * 256 + t];
    sm[t] = s;
    __syncthreads();
    if (t < 128) {
        float mu = sm[t] * (1.0f / NN);
        float var = sm[t + 128] * (1.0f / NN) - mu * mu;
        float sc = rsqrtf(var + EPSBN) * gamma[t];
        scaleshift[t] = sc;
        scaleshift[t + 128] = beta[t] - mu * sc;
    }
}

// ---------------- BN apply + relu, in place on split arrays ----------------
__global__ void k_bn_apply(u16* __restrict__ Hh, u16* __restrict__ Hl,
                           const float* __restrict__ scaleshift) {
    int idx = blockIdx.x * 256 + threadIdx.x;  // over NN*DIM/4
    int base = idx * 4;
    int col = base & 127;
    u16x4 hi = *reinterpret_cast<const u16x4*>(Hh + base);
    u16x4 lo = *reinterpret_cast<const u16x4*>(Hl + base);
#pragma unroll
    for (int j = 0; j < 4; j++) {
        float v = bf2f(hi[j]) + bf2f(lo[j]);
        v = fmaxf(v * scaleshift[col + j] + scaleshift[128 + col + j], 0.f);
        u16 h = f2bf(v);
        hi[j] = h;
        lo[j] = f2bf(v - bf2f(h));
    }
    *reinterpret_cast<u16x4*>(Hh + base) = hi;
    *reinterpret_cast<u16x4*>(Hl + base) = lo;
}

// ---------------- pooling: per-graph range slices (batch sorted) ----------------
__global__ void k_pool(const u16* __restrict__ Hh, const u16* __restrict__ Hl,
                       const int* __restrict__ gs, float* __restrict__ pSum,
                       float* __restrict__ pMax) {
    int g = blockIdx.x >> 3, slice = blockIdx.x & 7;
    int s0 = gs[g], s1 = gs[g + 1];
    int len = s1 - s0;
    int chunk = (len + 7) >> 3;
    int r0 = s0 + slice * chunk;
    int r1 = min(r0 + chunk, s1);
    int t = threadIdx.x;
    int c2 = (t & 63) * 2, half = t >> 6;
    float sa = 0.f, sb = 0.f, ma = 0.f, mb = 0.f;
    for (int r = r0 + half; r < r1; r += 4) {
        u32 h2 = *reinterpret_cast<const u32*>(Hh + r * DIM + c2);
        u32 l2 = *reinterpret_cast<const u32*>(Hl + r * DIM + c2);
        float v0 = __uint_as_float(h2 << 16) + __uint_as_float(l2 << 16);
        float v1 = __uint_as_float(h2 & 0xFFFF0000u) + __uint_as_float(l2 & 0xFFFF0000u);
        sa += v0; sb += v1;
        ma = fmaxf(ma, v0); mb = fmaxf(mb, v1);
    }
    __shared__ float ls[4][128], lm[4][128];
    ls[half][c2] = sa; ls[half][c2 + 1] = sb;
    lm[half][c2] = ma; lm[half][c2 + 1] = mb;
    __syncthreads();
    if (t < 128) {
        float s = ls[0][t] + ls[1][t] + ls[2][t] + ls[3][t];
        float m = fmaxf(fmaxf(lm[0][t], lm[1][t]), fmaxf(lm[2][t], lm[3][t]));
        atomicAdd(&pSum[g * DIM + t], s);
        atomicMax((int*)&pMax[g * DIM + t], __float_as_int(m));  // values >= 0, init 0
    }
}

// ---------------- classifier MLP: one block per graph ----------------
__global__ void k_mlp(const float* __restrict__ pSum, const float* __restrict__ pMax,
                      const int* __restrict__ gs,
                      const float* __restrict__ W1, const float* __restrict__ b1,
                      const float* __restrict__ W2, const float* __restrict__ b2,
                      const float* __restrict__ W3, const float* __restrict__ b3,
                      float* __restrict__ out) {
    __shared__ float g[256], y1[128], y2[64];
    int gi = blockIdx.x;
    int t = threadIdx.x;  // 128 threads
    int cnt = gs[gi + 1] - gs[gi];
    float inv = 1.0f / fmaxf((float)cnt, 1.0f);
    g[t] = pSum[gi * DIM + t] * inv;
    g[128 + t] = pMax[gi * DIM + t];
    __syncthreads();
    float a = b1[t];
    for (int k = 0; k < 256; k++) a += g[k] * W1[k * 128 + t];
    y1[t] = fmaxf(a, 0.f);
    __syncthreads();
    if (t < 64) {
        float a2 = b2[t];
        for (int k = 0; k < 128; k++) a2 += y1[k] * W2[k * 64 + t];
        y2[t] = fmaxf(a2, 0.f);
    }
    __syncthreads();
    if (t < 64) {
        float p = y2[t] * W3[t];
#pragma unroll
        for (int off = 32; off; off >>= 1) p += __shfl_down(p, off);
        if (t == 0) out[gi] = p + b3[0];
    }
}

extern "C" void kernel_launch(void* const* d_in, const int* in_sizes, int n_in,
                              void* d_out, int out_size, void* d_ws, size_t ws_size,
                              hipStream_t stream) {
    const float* x     = (const float*)d_in[0];
    const int*   ei    = (const int*)d_in[1];
    const int*   batch = (const int*)d_in[2];
    const float* Wl    = (const float*)d_in[3];
    const float* bl    = (const float*)d_in[4];
    const float* Wr    = (const float*)d_in[5];
    const float* gamma = (const float*)d_in[6];
    const float* beta  = (const float*)d_in[7];
    const float* W1    = (const float*)d_in[8];
    const float* b1    = (const float*)d_in[9];
    const float* W2    = (const float*)d_in[10];
    const float* b2    = (const float*)d_in[11];
    const float* W3    = (const float*)d_in[12];
    const float* b3    = (const float*)d_in[13];
    float* out = (float*)d_out;

    char* p = (char*)d_ws;
    size_t off = 0;
    auto alloc = [&](size_t bytes) -> void* {
        void* r = p + off;
        off += (bytes + 255) & ~(size_t)255;
        return r;
    };
    const size_t HB = (size_t)NN * DIM * 2;  // one split component
    u16* Xh   = (u16*)alloc(HB);   // h_in / hB (aliased: X dead before hB written)
    u16* Xl   = (u16*)alloc(HB);
    u16* hAh  = (u16*)alloc(HB);
    u16* hAl  = (u16*)alloc(HB);
    u16* aggh = (u16*)alloc(HB);
    u16* aggl = (u16*)alloc(HB);
    int*   ssrc      = (int*)alloc((size_t)NE * 4);
    u16*   Wth       = (u16*)alloc((size_t)8 * 128 * 256 * 2);
    u16*   Wtl       = (u16*)alloc((size_t)8 * 128 * 256 * 2);
    float* partials  = (float*)alloc((size_t)NBLK * 256 * 4);
    int*   deg       = (int*)alloc(NN * 4);
    float* inv_deg   = (float*)alloc(NN * 4);
    int*   row_start = (int*)alloc((NN + 1) * 4);
    int*   cursor    = (int*)alloc(NN * 4);
    int*   bsum      = (int*)alloc(512 * 4);
    int*   gs        = (int*)alloc((NG + 1) * 4);
    float* scaleshift= (float*)alloc(256 * 4);
    float* pSum      = (float*)alloc(NG * DIM * 4);
    float* pMax      = (float*)alloc(NG * DIM * 4);

    const int nbN = (NN + 255) / 256;
    const int nbE = (NE + 255) / 256;
    const int nbQ = NN * DIM / 4 / 256;  // 12500
    const int aggGrid = (NN + 3) / 4;

    // CSR build + graph bounds
    hipMemsetAsync(deg, 0, NN * 4, stream);
    k_deg_hist<<<nbE, 256, 0, stream>>>(ei, deg);
    k_inv_deg<<<nbN, 256, 0, stream>>>(deg, inv_deg);
    k_scan1<<<nbN, 256, 0, stream>>>(deg, row_start, bsum);
    k_scan2<<<1, 512, 0, stream>>>(bsum, nbN);
    k_scan3<<<nbN, 256, 0, stream>>>(row_start, bsum);
    k_copy_cursor<<<nbN, 256, 0, stream>>>(row_start, cursor);
    k_sort<<<nbE, 256, 0, stream>>>(ei, cursor, ssrc);
    k_bounds<<<1, 128, 0, stream>>>(batch, gs);

    // input + weight prep
    k_split_x<<<nbQ, 256, 0, stream>>>(x, Xh, Xl);
    k_prep_w<<<8 * 128 * 256 / 256, 256, 0, stream>>>(Wl, Wr, Wth, Wtl);

    for (int b = 0; b < 4; b++) {
        int c0 = 2 * b, c1 = 2 * b + 1;
        const u16* W0h = Wth + (size_t)c0 * 128 * 256;
        const u16* W0l = Wtl + (size_t)c0 * 128 * 256;
        const u16* W1h = Wth + (size_t)c1 * 128 * 256;
        const u16* W1l = Wtl + (size_t)c1 * 128 * 256;
        k_aggregate<<<aggGrid, 256, 0, stream>>>(Xh, Xl, row_start, ssrc, inv_deg, aggh, aggl);
        k_gemm<true, false><<<NBLK, 256, 0, stream>>>(aggh, aggl, Xh, Xl, W0h, W0l,
                                                      bl + c0 * DIM, hAh, hAl, partials);
        k_aggregate<<<aggGrid, 256, 0, stream>>>(hAh, hAl, row_start, ssrc, inv_deg, aggh, aggl);
        k_gemm<false, true><<<NBLK, 256, 0, stream>>>(aggh, aggl, hAh, hAl, W1h, W1l,
                                                      bl + c1 * DIM, Xh, Xl, partials);
        k_bn_reduce<<<1, 256, 0, stream>>>(partials, gamma + b * DIM, beta + b * DIM, scaleshift);
        k_bn_apply<<<nbQ, 256, 0, stream>>>(Xh, Xl, scaleshift);
    }

    // pooling + classifier
    hipMemsetAsync(pSum, 0, NG * DIM * 4, stream);
    hipMemsetAsync(pMax, 0, NG * DIM * 4, stream);
    k_pool<<<NG * 8, 256, 0, stream>>>(Xh, Xl, gs, pSum, pMax);
    k_mlp<<<NG, 128, 0, stream>>>(pSum, pMax, gs, W1, b1, W2, b2, W3, b3, out);
}

// Round 3
// 1791.327 us; speedup vs baseline: 2.0939x; 1.2544x over previous
//
#include <hip/hip_runtime.h>
#include <hip/hip_bf16.h>
#include <math.h>

#define NN 100000
#define NE 1600000
#define DIM 128
#define NG 64
#define EPSBN 1e-5f
#define NBLK 782  // (NN+127)/128

typedef unsigned int u32;
typedef unsigned short u16;
typedef __attribute__((ext_vector_type(8))) short bf8_t;   // 8 x bf16
typedef __attribute__((ext_vector_type(4))) float f4_t;    // 4 x f32
typedef __attribute__((ext_vector_type(4))) unsigned short u16x4;
#define MFMA(a, b, c) __builtin_amdgcn_mfma_f32_16x16x32_bf16((a), (b), (c), 0, 0, 0)

__device__ __forceinline__ u16 f2bf(float f) {
    u32 u = __float_as_uint(f);
    u32 r = u + 0x7FFFu + ((u >> 16) & 1u);   // round-to-nearest-even
    return (u16)(r >> 16);
}
__device__ __forceinline__ float bf2f(u16 h) { return __uint_as_float(((u32)h) << 16); }

// ---------------- degree / CSR build ----------------
__global__ void k_deg_hist(const int* __restrict__ ei, int* __restrict__ deg) {
    int e = blockIdx.x * blockDim.x + threadIdx.x;
    if (e < NE) atomicAdd(&deg[ei[NE + e]], 1);
}

__global__ void k_inv_deg(const int* __restrict__ deg, float* __restrict__ inv_deg) {
    int i = blockIdx.x * blockDim.x + threadIdx.x;
    if (i < NN) {
        int d = deg[i];
        inv_deg[i] = 1.0f / (float)(d > 1 ? d : 1);
    }
}

#define SCAN_B 256
__global__ void k_scan1(const int* __restrict__ deg, int* __restrict__ row_start,
                        int* __restrict__ bsum) {
    __shared__ int s[SCAN_B];
    int t = threadIdx.x;
    int i = blockIdx.x * SCAN_B + t;
    int v = (i < NN) ? deg[i] : 0;
    s[t] = v;
    for (int off = 1; off < SCAN_B; off <<= 1) {
        __syncthreads();
        int x = (t >= off) ? s[t - off] : 0;
        __syncthreads();
        s[t] += x;
    }
    if (i < NN) row_start[i + 1] = s[t];
    if (t == SCAN_B - 1) bsum[blockIdx.x] = s[t];
}

__global__ void k_scan2(int* __restrict__ bsum, int nb) {
    __shared__ int s[512];
    int t = threadIdx.x;
    int v = (t < nb) ? bsum[t] : 0;
    s[t] = v;
    for (int off = 1; off < 512; off <<= 1) {
        __syncthreads();
        int x = (t >= off) ? s[t - off] : 0;
        __syncthreads();
        s[t] += x;
    }
    if (t < nb) bsum[t] = s[t] - v;
}

__global__ void k_scan3(int* __restrict__ row_start, const int* __restrict__ bsum) {
    int i = blockIdx.x * blockDim.x + threadIdx.x;
    if (i < NN) row_start[i + 1] += bsum[i / SCAN_B];
    if (i == 0) row_start[0] = 0;
}

__global__ void k_copy_cursor(const int* __restrict__ row_start, int* __restrict__ cursor) {
    int i = blockIdx.x * blockDim.x + threadIdx.x;
    if (i < NN) cursor[i] = row_start[i];
}

__global__ void k_sort(const int* __restrict__ ei, int* __restrict__ cursor,
                       int* __restrict__ sorted_src) {
    int e = blockIdx.x * blockDim.x + threadIdx.x;
    if (e < NE) {
        int s = ei[e];
        int d = ei[NE + e];
        int pos = atomicAdd(&cursor[d], 1);
        sorted_src[pos] = s;
    }
}

// graph ranges via binary search (batch is sorted)
__global__ void k_bounds(const int* __restrict__ batch, int* __restrict__ gs) {
    int g = threadIdx.x;
    if (g > NG) return;
    int lo = 0, hi = NN;
    while (lo < hi) {
        int mid = (lo + hi) >> 1;
        if (batch[mid] < g) lo = mid + 1; else hi = mid;
    }
    gs[g] = lo;
}

// ---------------- fp32 x -> split bf16 (hi, lo) ----------------
__global__ void k_split_x(const float* __restrict__ x, u16* __restrict__ Xh,
                          u16* __restrict__ Xl) {
    int idx = blockIdx.x * 256 + threadIdx.x;
    int base = idx * 4;
    float4 v = *reinterpret_cast<const float4*>(&x[base]);
    u16x4 hi, lo;
    float vv[4] = {v.x, v.y, v.z, v.w};
#pragma unroll
    for (int j = 0; j < 4; j++) {
        u16 h = f2bf(vv[j]);
        hi[j] = h;
        lo[j] = f2bf(vv[j] - bf2f(h));
    }
    *reinterpret_cast<u16x4*>(&Xh[base]) = hi;
    *reinterpret_cast<u16x4*>(&Xl[base]) = lo;
}

// ---------------- weight prep: transpose+stack+split ----------------
__global__ void k_prep_w(const float* __restrict__ Wl, const float* __restrict__ Wr,
                         u16* __restrict__ Wth, u16* __restrict__ Wtl) {
    int idx = blockIdx.x * 256 + threadIdx.x;  // 8*128*256
    int k = idx & 255;
    int col = (idx >> 8) & 127;
    int c = idx >> 15;
    float v = (k < 128) ? Wl[(c * 128 + k) * 128 + col] : Wr[(c * 128 + (k - 128)) * 128 + col];
    u16 h = f2bf(v);
    Wth[idx] = h;
    Wtl[idx] = f2bf(v - bf2f(h));
}

// ---------------- mean aggregation: hi-only gather, split output ----------------
__global__ void k_aggregate(const u16* __restrict__ Hh,
                            const int* __restrict__ row_start, const int* __restrict__ ssrc,
                            const float* __restrict__ inv_deg,
                            u16* __restrict__ Ah, u16* __restrict__ Al) {
    int wid = blockIdx.x * 4 + (threadIdx.x >> 6);
    int lane = threadIdx.x & 63;
    if (wid >= NN) return;
    int beg = row_start[wid], end = row_start[wid + 1];
    float a0 = 0.f, a1 = 0.f;
    for (int base = beg; base < end; base += 64) {
        int nv = end - base;
        int idx = base + (lane < nv ? lane : 0);
        int sv = ssrc[idx];
        int n = nv < 64 ? nv : 64;
        int j = 0;
        for (; j + 1 < n; j += 2) {
            int s0 = __shfl(sv, j);
            int s1 = __shfl(sv, j + 1);
            u32 p = *reinterpret_cast<const u32*>(Hh + s0 * DIM + lane * 2);
            u32 q = *reinterpret_cast<const u32*>(Hh + s1 * DIM + lane * 2);
            a0 += __uint_as_float(p << 16) + __uint_as_float(q << 16);
            a1 += __uint_as_float(p & 0xFFFF0000u) + __uint_as_float(q & 0xFFFF0000u);
        }
        if (j < n) {
            int s0 = __shfl(sv, j);
            u32 p = *reinterpret_cast<const u32*>(Hh + s0 * DIM + lane * 2);
            a0 += __uint_as_float(p << 16);
            a1 += __uint_as_float(p & 0xFFFF0000u);
        }
    }
    float sc = inv_deg[wid];
    a0 *= sc; a1 *= sc;
    u16 h0 = f2bf(a0), h1 = f2bf(a1);
    u16 l0 = f2bf(a0 - bf2f(h0)), l1 = f2bf(a1 - bf2f(h1));
    *reinterpret_cast<u32*>(Ah + wid * DIM + lane * 2) = (u32)h0 | ((u32)h1 << 16);
    *reinterpret_cast<u32*>(Al + wid * DIM + lane * 2) = (u32)l0 | ((u32)l1 << 16);
}

// ---------------- fused conv GEMM (MFMA, split-bf16 = fp32-accurate) ---------
template <bool RELU, bool STATS>
__global__ __launch_bounds__(256) void k_gemm(
    const u16* __restrict__ A1h, const u16* __restrict__ A1l,
    const u16* __restrict__ A2h, const u16* __restrict__ A2l,
    const u16* __restrict__ Wth, const u16* __restrict__ Wtl,
    const float* __restrict__ bias,
    u16* __restrict__ Oh, u16* __restrict__ Ol,
    float* __restrict__ partials) {
    __shared__ float cs[128], cq[128];
    int t = threadIdx.x;
    if (STATS) {
        if (t < 128) { cs[t] = 0.f; cq[t] = 0.f; }
        __syncthreads();
    }
    int w = t >> 6, l = t & 63;
    int rl = l & 15, kg = l >> 4;
    int rbase = blockIdx.x * 128 + w * 32;
    int row0 = rbase + rl, row1 = rbase + 16 + rl;
    int row0c = min(row0, NN - 1), row1c = min(row1, NN - 1);

    f4_t acc[2][8];
#pragma unroll
    for (int i = 0; i < 2; i++)
#pragma unroll
        for (int j = 0; j < 8; j++) acc[i][j] = (f4_t){0.f, 0.f, 0.f, 0.f};

#pragma unroll
    for (int ks = 0; ks < 4; ++ks) {  // K half 1: A1 (agg)
        int k0 = ks * 32 + kg * 8;
        bf8_t a0h = *reinterpret_cast<const bf8_t*>(A1h + row0c * DIM + k0);
        bf8_t a0l = *reinterpret_cast<const bf8_t*>(A1l + row0c * DIM + k0);
        bf8_t a1h = *reinterpret_cast<const bf8_t*>(A1h + row1c * DIM + k0);
        bf8_t a1l = *reinterpret_cast<const bf8_t*>(A1l + row1c * DIM + k0);
#pragma unroll
        for (int cf = 0; cf < 8; ++cf) {
            int wo = (cf * 16 + rl) * 256 + k0;
            bf8_t bh = *reinterpret_cast<const bf8_t*>(Wth + wo);
            bf8_t bl_ = *reinterpret_cast<const bf8_t*>(Wtl + wo);
            acc[0][cf] = MFMA(a0h, bh, acc[0][cf]);
            acc[0][cf] = MFMA(a0h, bl_, acc[0][cf]);
            acc[0][cf] = MFMA(a0l, bh, acc[0][cf]);
            acc[1][cf] = MFMA(a1h, bh, acc[1][cf]);
            acc[1][cf] = MFMA(a1h, bl_, acc[1][cf]);
            acc[1][cf] = MFMA(a1l, bh, acc[1][cf]);
        }
    }
#pragma unroll
    for (int ks = 0; ks < 4; ++ks) {  // K half 2: A2 (h)
        int k0 = ks * 32 + kg * 8;
        bf8_t a0h = *reinterpret_cast<const bf8_t*>(A2h + row0c * DIM + k0);
        bf8_t a0l = *reinterpret_cast<const bf8_t*>(A2l + row0c * DIM + k0);
        bf8_t a1h = *reinterpret_cast<const bf8_t*>(A2h + row1c * DIM + k0);
        bf8_t a1l = *reinterpret_cast<const bf8_t*>(A2l + row1c * DIM + k0);
#pragma unroll
        for (int cf = 0; cf < 8; ++cf) {
            int wo = (cf * 16 + rl) * 256 + 128 + k0;
            bf8_t bh = *reinterpret_cast<const bf8_t*>(Wth + wo);
            bf8_t bl_ = *reinterpret_cast<const bf8_t*>(Wtl + wo);
            acc[0][cf] = MFMA(a0h, bh, acc[0][cf]);
            acc[0][cf] = MFMA(a0h, bl_, acc[0][cf]);
            acc[0][cf] = MFMA(a0l, bh, acc[0][cf]);
            acc[1][cf] = MFMA(a1h, bh, acc[1][cf]);
            acc[1][cf] = MFMA(a1h, bl_, acc[1][cf]);
            acc[1][cf] = MFMA(a1l, bh, acc[1][cf]);
        }
    }

    // epilogue: C/D layout col = lane&15, row = (lane>>4)*4 + i  [verified m89]
#pragma unroll
    for (int rf = 0; rf < 2; ++rf) {
        int rb = rbase + rf * 16 + kg * 4;
#pragma unroll
        for (int cf = 0; cf < 8; ++cf) {
            int col = cf * 16 + rl;
            float bv = bias[col];
            float s = 0.f, q = 0.f;
#pragma unroll
            for (int i = 0; i < 4; ++i) {
                int row = rb + i;
                float v = acc[rf][cf][i] + bv;
                if (RELU) v = fmaxf(v, 0.f);
                if (row < NN) {
                    u16 hi = f2bf(v);
                    Oh[row * DIM + col] = hi;
                    Ol[row * DIM + col] = f2bf(v - bf2f(hi));
                    if (STATS) { s += v; q += v * v; }
                }
            }
            if (STATS) {
                s += __shfl_xor(s, 16); s += __shfl_xor(s, 32);
                q += __shfl_xor(q, 16); q += __shfl_xor(q, 32);
                if (l < 16) {
                    atomicAdd(&cs[col], s);
                    atomicAdd(&cq[col], q);
                }
            }
        }
    }
    if (STATS) {
        __syncthreads();
        partials[blockIdx.x * 256 + t] = (t < 128) ? cs[t] : cq[t - 128];
    }
}

// ---------------- BN: two-stage parallel reduce of partials ----------------
__global__ void k_bn_r1(const float* __restrict__ partials, float* __restrict__ colpart) {
    int t = threadIdx.x;
    int b = blockIdx.x;  // 32 blocks
    int b0 = b * 25, b1 = min(b0 + 25, NBLK);
    float s = 0.f;
    for (int i = b0; i < b1; ++i) s += partials[i * 256 + t];
    colpart[b * 256 + t] = s;
}

__global__ void k_bn_r2(const float* __restrict__ colpart, const float* __restrict__ gamma,
                        const float* __restrict__ beta, float* __restrict__ scaleshift) {
    __shared__ float sm[256];
    int t = threadIdx.x;
    float s = 0.f;
#pragma unroll
    for (int b = 0; b < 32; ++b) s += colpart[b * 256 + t];
    sm[t] = s;
    __syncthreads();
    if (t < 128) {
        float mu = sm[t] * (1.0f / NN);
        float var = sm[t + 128] * (1.0f / NN) - mu * mu;
        float sc = rsqrtf(var + EPSBN) * gamma[t];
        scaleshift[t] = sc;
        scaleshift[t + 128] = beta[t] - mu * sc;
    }
}

// ---------------- BN apply + relu, in place on split arrays ----------------
__global__ void k_bn_apply(u16* __restrict__ Hh, u16* __restrict__ Hl,
                           const float* __restrict__ scaleshift) {
    int idx = blockIdx.x * 256 + threadIdx.x;
    int base = idx * 4;
    int col = base & 127;
    u16x4 hi = *reinterpret_cast<const u16x4*>(Hh + base);
    u16x4 lo = *reinterpret_cast<const u16x4*>(Hl + base);
#pragma unroll
    for (int j = 0; j < 4; j++) {
        float v = bf2f(hi[j]) + bf2f(lo[j]);
        v = fmaxf(v * scaleshift[col + j] + scaleshift[128 + col + j], 0.f);
        u16 h = f2bf(v);
        hi[j] = h;
        lo[j] = f2bf(v - bf2f(h));
    }
    *reinterpret_cast<u16x4*>(Hh + base) = hi;
    *reinterpret_cast<u16x4*>(Hl + base) = lo;
}

// ---------------- pooling: per-graph range slices (batch sorted) ----------------
__global__ void k_pool(const u16* __restrict__ Hh, const u16* __restrict__ Hl,
                       const int* __restrict__ gs, float* __restrict__ pSum,
                       float* __restrict__ pMax) {
    int g = blockIdx.x >> 3, slice = blockIdx.x & 7;
    int s0 = gs[g], s1 = gs[g + 1];
    int len = s1 - s0;
    int chunk = (len + 7) >> 3;
    int r0 = s0 + slice * chunk;
    int r1 = min(r0 + chunk, s1);
    int t = threadIdx.x;
    int c2 = (t & 63) * 2, half = t >> 6;
    float sa = 0.f, sb = 0.f, ma = 0.f, mb = 0.f;
    for (int r = r0 + half; r < r1; r += 4) {
        u32 h2 = *reinterpret_cast<const u32*>(Hh + r * DIM + c2);
        u32 l2 = *reinterpret_cast<const u32*>(Hl + r * DIM + c2);
        float v0 = __uint_as_float(h2 << 16) + __uint_as_float(l2 << 16);
        float v1 = __uint_as_float(h2 & 0xFFFF0000u) + __uint_as_float(l2 & 0xFFFF0000u);
        sa += v0; sb += v1;
        ma = fmaxf(ma, v0); mb = fmaxf(mb, v1);
    }
    __shared__ float ls[4][128], lm[4][128];
    ls[half][c2] = sa; ls[half][c2 + 1] = sb;
    lm[half][c2] = ma; lm[half][c2 + 1] = mb;
    __syncthreads();
    if (t < 128) {
        float s = ls[0][t] + ls[1][t] + ls[2][t] + ls[3][t];
        float m = fmaxf(fmaxf(lm[0][t], lm[1][t]), fmaxf(lm[2][t], lm[3][t]));
        atomicAdd(&pSum[g * DIM + t], s);
        atomicMax((int*)&pMax[g * DIM + t], __float_as_int(m));  // values >= 0, init 0
    }
}

// ---------------- classifier MLP: one block per graph ----------------
__global__ void k_mlp(const float* __restrict__ pSum, const float* __restrict__ pMax,
                      const int* __restrict__ gs,
                      const float* __restrict__ W1, const float* __restrict__ b1,
                      const float* __restrict__ W2, const float* __restrict__ b2,
                      const float* __restrict__ W3, const float* __restrict__ b3,
                      float* __restrict__ out) {
    __shared__ float g[256], y1[128], y2[64];
    int gi = blockIdx.x;
    int t = threadIdx.x;  // 128 threads
    int cnt = gs[gi + 1] - gs[gi];
    float inv = 1.0f / fmaxf((float)cnt, 1.0f);
    g[t] = pSum[gi * DIM + t] * inv;
    g[128 + t] = pMax[gi * DIM + t];
    __syncthreads();
    float a = b1[t];
    for (int k = 0; k < 256; k++) a += g[k] * W1[k * 128 + t];
    y1[t] = fmaxf(a, 0.f);
    __syncthreads();
    if (t < 64) {
        float a2 = b2[t];
        for (int k = 0; k < 128; k++) a2 += y1[k] * W2[k * 64 + t];
        y2[t] = fmaxf(a2, 0.f);
    }
    __syncthreads();
    if (t < 64) {
        float p = y2[t] * W3[t];
#pragma unroll
        for (int off = 32; off; off >>= 1) p += __shfl_down(p, off);
        if (t == 0) out[gi] = p + b3[0];
    }
}

extern "C" void kernel_launch(void* const* d_in, const int* in_sizes, int n_in,
                              void* d_out, int out_size, void* d_ws, size_t ws_size,
                              hipStream_t stream) {
    const float* x     = (const float*)d_in[0];
    const int*   ei    = (const int*)d_in[1];
    const int*   batch = (const int*)d_in[2];
    const float* Wl    = (const float*)d_in[3];
    const float* bl    = (const float*)d_in[4];
    const float* Wr    = (const float*)d_in[5];
    const float* gamma = (const float*)d_in[6];
    const float* beta  = (const float*)d_in[7];
    const float* W1    = (const float*)d_in[8];
    const float* b1    = (const float*)d_in[9];
    const float* W2    = (const float*)d_in[10];
    const float* b2    = (const float*)d_in[11];
    const float* W3    = (const float*)d_in[12];
    const float* b3    = (const float*)d_in[13];
    float* out = (float*)d_out;

    char* p = (char*)d_ws;
    size_t off = 0;
    auto alloc = [&](size_t bytes) -> void* {
        void* r = p + off;
        off += (bytes + 255) & ~(size_t)255;
        return r;
    };
    const size_t HB = (size_t)NN * DIM * 2;
    u16* Xh   = (u16*)alloc(HB);
    u16* Xl   = (u16*)alloc(HB);
    u16* hAh  = (u16*)alloc(HB);
    u16* hAl  = (u16*)alloc(HB);
    u16* aggh = (u16*)alloc(HB);
    u16* aggl = (u16*)alloc(HB);
    int*   ssrc      = (int*)alloc((size_t)NE * 4);
    u16*   Wth       = (u16*)alloc((size_t)8 * 128 * 256 * 2);
    u16*   Wtl       = (u16*)alloc((size_t)8 * 128 * 256 * 2);
    float* partials  = (float*)alloc((size_t)NBLK * 256 * 4);
    float* colpart   = (float*)alloc(32 * 256 * 4);
    int*   deg       = (int*)alloc(NN * 4);
    float* inv_deg   = (float*)alloc(NN * 4);
    int*   row_start = (int*)alloc((NN + 1) * 4);
    int*   cursor    = (int*)alloc(NN * 4);
    int*   bsum      = (int*)alloc(512 * 4);
    int*   gs        = (int*)alloc((NG + 1) * 4);
    float* scaleshift= (float*)alloc(256 * 4);
    float* pSum      = (float*)alloc(NG * DIM * 4);
    float* pMax      = (float*)alloc(NG * DIM * 4);

    const int nbN = (NN + 255) / 256;
    const int nbE = (NE + 255) / 256;
    const int nbQ = NN * DIM / 4 / 256;  // 12500
    const int aggGrid = (NN + 3) / 4;

    // CSR build + graph bounds
    hipMemsetAsync(deg, 0, NN * 4, stream);
    k_deg_hist<<<nbE, 256, 0, stream>>>(ei, deg);
    k_inv_deg<<<nbN, 256, 0, stream>>>(deg, inv_deg);
    k_scan1<<<nbN, 256, 0, stream>>>(deg, row_start, bsum);
    k_scan2<<<1, 512, 0, stream>>>(bsum, nbN);
    k_scan3<<<nbN, 256, 0, stream>>>(row_start, bsum);
    k_copy_cursor<<<nbN, 256, 0, stream>>>(row_start, cursor);
    k_sort<<<nbE, 256, 0, stream>>>(ei, cursor, ssrc);
    k_bounds<<<1, 128, 0, stream>>>(batch, gs);

    // input + weight prep
    k_split_x<<<nbQ, 256, 0, stream>>>(x, Xh, Xl);
    k_prep_w<<<8 * 128 * 256 / 256, 256, 0, stream>>>(Wl, Wr, Wth, Wtl);

    for (int b = 0; b < 4; b++) {
        int c0 = 2 * b, c1 = 2 * b + 1;
        const u16* W0h = Wth + (size_t)c0 * 128 * 256;
        const u16* W0l = Wtl + (size_t)c0 * 128 * 256;
        const u16* W1h = Wth + (size_t)c1 * 128 * 256;
        const u16* W1l = Wtl + (size_t)c1 * 128 * 256;
        k_aggregate<<<aggGrid, 256, 0, stream>>>(Xh, row_start, ssrc, inv_deg, aggh, aggl);
        k_gemm<true, false><<<NBLK, 256, 0, stream>>>(aggh, aggl, Xh, Xl, W0h, W0l,
                                                      bl + c0 * DIM, hAh, hAl, partials);
        k_aggregate<<<aggGrid, 256, 0, stream>>>(hAh, row_start, ssrc, inv_deg, aggh, aggl);
        k_gemm<false, true><<<NBLK, 256, 0, stream>>>(aggh, aggl, hAh, hAl, W1h, W1l,
                                                      bl + c1 * DIM, Xh, Xl, partials);
        k_bn_r1<<<32, 256, 0, stream>>>(partials, colpart);
        k_bn_r2<<<1, 256, 0, stream>>>(colpart, gamma + b * DIM, beta + b * DIM, scaleshift);
        k_bn_apply<<<nbQ, 256, 0, stream>>>(Xh, Xl, scaleshift);
    }

    // pooling + classifier
    hipMemsetAsync(pSum, 0, NG * DIM * 4, stream);
    hipMemsetAsync(pMax, 0, NG * DIM * 4, stream);
    k_pool<<<NG * 8, 256, 0, stream>>>(Xh, Xl, gs, pSum, pMax);
    k_mlp<<<NG, 128, 0, stream>>>(pSum, pMax, gs, W1, b1, W2, b2, W3, b3, out);
}

// Round 4
// 1702.405 us; speedup vs baseline: 2.2032x; 1.0522x over previous
//
#include <hip/hip_runtime.h>
#include <hip/hip_bf16.h>
#include <math.h>

#define NN 100000
#define NE 1600000
#define DIM 128
#define NG 64
#define EPSBN 1e-5f
#define NBLK 782      // (NN+127)/128
#define SORT_WIN 12500  // NN/8 dst-window for scatter passes

typedef unsigned int u32;
typedef unsigned short u16;
typedef __attribute__((ext_vector_type(8))) short bf8_t;   // 8 x bf16
typedef __attribute__((ext_vector_type(4))) float f4_t;    // 4 x f32
typedef __attribute__((ext_vector_type(4))) unsigned short u16x4;
#define MFMA(a, b, c) __builtin_amdgcn_mfma_f32_16x16x32_bf16((a), (b), (c), 0, 0, 0)

__device__ __forceinline__ u16 f2bf(float f) {
    u32 u = __float_as_uint(f);
    u32 r = u + 0x7FFFu + ((u >> 16) & 1u);   // round-to-nearest-even
    return (u16)(r >> 16);
}
__device__ __forceinline__ float bf2f(u16 h) { return __uint_as_float(((u32)h) << 16); }

// ---------------- degree / CSR build ----------------
__global__ void k_deg_hist(const int* __restrict__ ei, int* __restrict__ deg) {
    int e = blockIdx.x * blockDim.x + threadIdx.x;
    if (e < NE) atomicAdd(&deg[ei[NE + e]], 1);
}

#define SCAN_B 256
__global__ void k_scan1(const int* __restrict__ deg, int* __restrict__ row_start,
                        int* __restrict__ bsum, float* __restrict__ inv_deg) {
    __shared__ int s[SCAN_B];
    int t = threadIdx.x;
    int i = blockIdx.x * SCAN_B + t;
    int v = (i < NN) ? deg[i] : 0;
    if (i < NN) inv_deg[i] = 1.0f / (float)(v > 1 ? v : 1);
    s[t] = v;
    for (int off = 1; off < SCAN_B; off <<= 1) {
        __syncthreads();
        int x = (t >= off) ? s[t - off] : 0;
        __syncthreads();
        s[t] += x;
    }
    if (i < NN) row_start[i + 1] = s[t];
    if (t == SCAN_B - 1) bsum[blockIdx.x] = s[t];
}

__global__ void k_scan2(int* __restrict__ bsum, int nb) {
    __shared__ int s[512];
    int t = threadIdx.x;
    int v = (t < nb) ? bsum[t] : 0;
    s[t] = v;
    for (int off = 1; off < 512; off <<= 1) {
        __syncthreads();
        int x = (t >= off) ? s[t - off] : 0;
        __syncthreads();
        s[t] += x;
    }
    if (t < nb) bsum[t] = s[t] - v;
}

__global__ void k_scan3(int* __restrict__ row_start, const int* __restrict__ bsum,
                        int* __restrict__ cursor) {
    int i = blockIdx.x * blockDim.x + threadIdx.x;
    if (i < NN) {
        int v = row_start[i + 1] + bsum[i / SCAN_B];
        row_start[i + 1] = v;
        if (i + 1 < NN) cursor[i + 1] = v;
    }
    if (i == 0) { row_start[0] = 0; cursor[0] = 0; }
}

// scatter src into CSR rows; 8 dst-window passes keep live write region ~800KB
// so partial 64B lines complete in L2 instead of thrashing to HBM.
__global__ void k_sort(const int* __restrict__ ei, int* __restrict__ cursor,
                       int* __restrict__ sorted_src) {
    int e = blockIdx.x * 256 + threadIdx.x;
    int s = ei[e];
    int d = ei[NE + e];
    int w = d / SORT_WIN;  // 0..7
#pragma unroll
    for (int p = 0; p < 8; ++p) {
        if (w == p) {
            int pos = atomicAdd(&cursor[d], 1);
            sorted_src[pos] = s;
        }
        __syncthreads();  // pace blocks through windows together
    }
}

// graph ranges via binary search (batch is sorted)
__global__ void k_bounds(const int* __restrict__ batch, int* __restrict__ gs) {
    int g = threadIdx.x;
    if (g > NG) return;
    int lo = 0, hi = NN;
    while (lo < hi) {
        int mid = (lo + hi) >> 1;
        if (batch[mid] < g) lo = mid + 1; else hi = mid;
    }
    gs[g] = lo;
}

// ---------------- fp32 x -> split bf16 (hi, lo) ----------------
__global__ void k_split_x(const float* __restrict__ x, u16* __restrict__ Xh,
                          u16* __restrict__ Xl) {
    int idx = blockIdx.x * 256 + threadIdx.x;
    int base = idx * 4;
    float4 v = *reinterpret_cast<const float4*>(&x[base]);
    u16x4 hi, lo;
    float vv[4] = {v.x, v.y, v.z, v.w};
#pragma unroll
    for (int j = 0; j < 4; j++) {
        u16 h = f2bf(vv[j]);
        hi[j] = h;
        lo[j] = f2bf(vv[j] - bf2f(h));
    }
    *reinterpret_cast<u16x4*>(&Xh[base]) = hi;
    *reinterpret_cast<u16x4*>(&Xl[base]) = lo;
}

// ---------------- weight prep: transpose+stack+split ----------------
__global__ void k_prep_w(const float* __restrict__ Wl, const float* __restrict__ Wr,
                         u16* __restrict__ Wth, u16* __restrict__ Wtl) {
    int idx = blockIdx.x * 256 + threadIdx.x;  // 8*128*256
    int k = idx & 255;
    int col = (idx >> 8) & 127;
    int c = idx >> 15;
    float v = (k < 128) ? Wl[(c * 128 + k) * 128 + col] : Wr[(c * 128 + (k - 128)) * 128 + col];
    u16 h = f2bf(v);
    Wth[idx] = h;
    Wtl[idx] = f2bf(v - bf2f(h));
}

// ---------------- mean aggregation: half-wave per edge, 2 rows per load instr ---
__global__ void k_aggregate(const u16* __restrict__ Hh,
                            const int* __restrict__ row_start, const int* __restrict__ ssrc,
                            const float* __restrict__ inv_deg,
                            u16* __restrict__ Ah, u16* __restrict__ Al) {
    int wid = blockIdx.x * 4 + (threadIdx.x >> 6);
    int lane = threadIdx.x & 63;
    int half = lane >> 5;   // which edge of the pair this half-wave handles
    int cl = lane & 31;     // col group: cols [cl*4, cl*4+4)
    if (wid >= NN) return;
    int beg = row_start[wid], end = row_start[wid + 1];
    int n = end - beg;
    float a0 = 0.f, a1 = 0.f, a2 = 0.f, a3 = 0.f;
    for (int base = 0; base < n; base += 64) {
        int rem = n - base;
        int idx = beg + base + (lane < rem ? lane : 0);
        int sv = ssrc[idx];
        int m = rem < 64 ? rem : 64;
        int j = 0;
        for (; j + 4 <= m; j += 4) {  // 4 edges: 2 load instrs, 4 rows in flight
            int sA = __shfl(sv, j + half);
            int sB = __shfl(sv, j + 2 + half);
            uint2 vA = *reinterpret_cast<const uint2*>(
                reinterpret_cast<const u32*>(Hh + (size_t)sA * DIM) + cl * 2);
            uint2 vB = *reinterpret_cast<const uint2*>(
                reinterpret_cast<const u32*>(Hh + (size_t)sB * DIM) + cl * 2);
            a0 += __uint_as_float(vA.x << 16) + __uint_as_float(vB.x << 16);
            a1 += __uint_as_float(vA.x & 0xFFFF0000u) + __uint_as_float(vB.x & 0xFFFF0000u);
            a2 += __uint_as_float(vA.y << 16) + __uint_as_float(vB.y << 16);
            a3 += __uint_as_float(vA.y & 0xFFFF0000u) + __uint_as_float(vB.y & 0xFFFF0000u);
        }
        for (; j < m; j += 2) {  // tail: up to 2 edges, half-wave-guarded
            if (j + half < m) {
                int s0 = __shfl(sv, j + half);
                uint2 v = *reinterpret_cast<const uint2*>(
                    reinterpret_cast<const u32*>(Hh + (size_t)s0 * DIM) + cl * 2);
                a0 += __uint_as_float(v.x << 16);
                a1 += __uint_as_float(v.x & 0xFFFF0000u);
                a2 += __uint_as_float(v.y << 16);
                a3 += __uint_as_float(v.y & 0xFFFF0000u);
            }
        }
    }
    // fold half 1 into half 0 (same columns)
    a0 += __shfl_down(a0, 32);
    a1 += __shfl_down(a1, 32);
    a2 += __shfl_down(a2, 32);
    a3 += __shfl_down(a3, 32);
    if (half == 0) {
        float sc = inv_deg[wid];
        a0 *= sc; a1 *= sc; a2 *= sc; a3 *= sc;
        u16 h0 = f2bf(a0), h1 = f2bf(a1), h2 = f2bf(a2), h3 = f2bf(a3);
        u16 l0 = f2bf(a0 - bf2f(h0)), l1 = f2bf(a1 - bf2f(h1));
        u16 l2 = f2bf(a2 - bf2f(h2)), l3 = f2bf(a3 - bf2f(h3));
        uint2 hv = make_uint2((u32)h0 | ((u32)h1 << 16), (u32)h2 | ((u32)h3 << 16));
        uint2 lv = make_uint2((u32)l0 | ((u32)l1 << 16), (u32)l2 | ((u32)l3 << 16));
        *reinterpret_cast<uint2*>(Ah + (size_t)wid * DIM + cl * 4) = hv;
        *reinterpret_cast<uint2*>(Al + (size_t)wid * DIM + cl * 4) = lv;
    }
}

// ---------------- fused conv GEMM (MFMA, split-bf16 = fp32-accurate) ---------
template <bool RELU, bool STATS>
__global__ __launch_bounds__(256) void k_gemm(
    const u16* __restrict__ A1h, const u16* __restrict__ A1l,
    const u16* __restrict__ A2h, const u16* __restrict__ A2l,
    const u16* __restrict__ Wth, const u16* __restrict__ Wtl,
    const float* __restrict__ bias,
    u16* __restrict__ Oh, u16* __restrict__ Ol,
    float* __restrict__ partials) {
    __shared__ float cs[128], cq[128];
    int t = threadIdx.x;
    if (STATS) {
        if (t < 128) { cs[t] = 0.f; cq[t] = 0.f; }
        __syncthreads();
    }
    int w = t >> 6, l = t & 63;
    int rl = l & 15, kg = l >> 4;
    int rbase = blockIdx.x * 128 + w * 32;
    int row0 = rbase + rl, row1 = rbase + 16 + rl;
    int row0c = min(row0, NN - 1), row1c = min(row1, NN - 1);

    f4_t acc[2][8];
#pragma unroll
    for (int i = 0; i < 2; i++)
#pragma unroll
        for (int j = 0; j < 8; j++) acc[i][j] = (f4_t){0.f, 0.f, 0.f, 0.f};

#pragma unroll
    for (int ks = 0; ks < 4; ++ks) {  // K half 1: A1 (agg)
        int k0 = ks * 32 + kg * 8;
        bf8_t a0h = *reinterpret_cast<const bf8_t*>(A1h + row0c * DIM + k0);
        bf8_t a0l = *reinterpret_cast<const bf8_t*>(A1l + row0c * DIM + k0);
        bf8_t a1h = *reinterpret_cast<const bf8_t*>(A1h + row1c * DIM + k0);
        bf8_t a1l = *reinterpret_cast<const bf8_t*>(A1l + row1c * DIM + k0);
#pragma unroll
        for (int cf = 0; cf < 8; ++cf) {
            int wo = (cf * 16 + rl) * 256 + k0;
            bf8_t bh = *reinterpret_cast<const bf8_t*>(Wth + wo);
            bf8_t bl_ = *reinterpret_cast<const bf8_t*>(Wtl + wo);
            acc[0][cf] = MFMA(a0h, bh, acc[0][cf]);
            acc[0][cf] = MFMA(a0h, bl_, acc[0][cf]);
            acc[0][cf] = MFMA(a0l, bh, acc[0][cf]);
            acc[1][cf] = MFMA(a1h, bh, acc[1][cf]);
            acc[1][cf] = MFMA(a1h, bl_, acc[1][cf]);
            acc[1][cf] = MFMA(a1l, bh, acc[1][cf]);
        }
    }
#pragma unroll
    for (int ks = 0; ks < 4; ++ks) {  // K half 2: A2 (h)
        int k0 = ks * 32 + kg * 8;
        bf8_t a0h = *reinterpret_cast<const bf8_t*>(A2h + row0c * DIM + k0);
        bf8_t a0l = *reinterpret_cast<const bf8_t*>(A2l + row0c * DIM + k0);
        bf8_t a1h = *reinterpret_cast<const bf8_t*>(A2h + row1c * DIM + k0);
        bf8_t a1l = *reinterpret_cast<const bf8_t*>(A2l + row1c * DIM + k0);
#pragma unroll
        for (int cf = 0; cf < 8; ++cf) {
            int wo = (cf * 16 + rl) * 256 + 128 + k0;
            bf8_t bh = *reinterpret_cast<const bf8_t*>(Wth + wo);
            bf8_t bl_ = *reinterpret_cast<const bf8_t*>(Wtl + wo);
            acc[0][cf] = MFMA(a0h, bh, acc[0][cf]);
            acc[0][cf] = MFMA(a0h, bl_, acc[0][cf]);
            acc[0][cf] = MFMA(a0l, bh, acc[0][cf]);
            acc[1][cf] = MFMA(a1h, bh, acc[1][cf]);
            acc[1][cf] = MFMA(a1h, bl_, acc[1][cf]);
            acc[1][cf] = MFMA(a1l, bh, acc[1][cf]);
        }
    }

    // epilogue: C/D layout col = lane&15, row = (lane>>4)*4 + i  [verified m89]
#pragma unroll
    for (int rf = 0; rf < 2; ++rf) {
        int rb = rbase + rf * 16 + kg * 4;
#pragma unroll
        for (int cf = 0; cf < 8; ++cf) {
            int col = cf * 16 + rl;
            float bv = bias[col];
            float s = 0.f, q = 0.f;
#pragma unroll
            for (int i = 0; i < 4; ++i) {
                int row = rb + i;
                float v = acc[rf][cf][i] + bv;
                if (RELU) v = fmaxf(v, 0.f);
                if (row < NN) {
                    u16 hi = f2bf(v);
                    Oh[row * DIM + col] = hi;
                    Ol[row * DIM + col] = f2bf(v - bf2f(hi));
                    if (STATS) { s += v; q += v * v; }
                }
            }
            if (STATS) {
                s += __shfl_xor(s, 16); s += __shfl_xor(s, 32);
                q += __shfl_xor(q, 16); q += __shfl_xor(q, 32);
                if (l < 16) {
                    atomicAdd(&cs[col], s);
                    atomicAdd(&cq[col], q);
                }
            }
        }
    }
    if (STATS) {
        __syncthreads();
        partials[blockIdx.x * 256 + t] = (t < 128) ? cs[t] : cq[t - 128];
    }
}

// ---------------- BN: two-stage parallel reduce of partials ----------------
__global__ void k_bn_r1(const float* __restrict__ partials, float* __restrict__ colpart) {
    int t = threadIdx.x;
    int b = blockIdx.x;  // 32 blocks
    int b0 = b * 25, b1 = min(b0 + 25, NBLK);
    float s = 0.f;
    for (int i = b0; i < b1; ++i) s += partials[i * 256 + t];
    colpart[b * 256 + t] = s;
}

__global__ void k_bn_r2(const float* __restrict__ colpart, const float* __restrict__ gamma,
                        const float* __restrict__ beta, float* __restrict__ scaleshift) {
    __shared__ float sm[256];
    int t = threadIdx.x;
    float s = 0.f;
#pragma unroll
    for (int b = 0; b < 32; ++b) s += colpart[b * 256 + t];
    sm[t] = s;
    __syncthreads();
    if (t < 128) {
        float mu = sm[t] * (1.0f / NN);
        float var = sm[t + 128] * (1.0f / NN) - mu * mu;
        float sc = rsqrtf(var + EPSBN) * gamma[t];
        scaleshift[t] = sc;
        scaleshift[t + 128] = beta[t] - mu * sc;
    }
}

// ---------------- BN apply + relu, in place on split arrays ----------------
__global__ void k_bn_apply(u16* __restrict__ Hh, u16* __restrict__ Hl,
                           const float* __restrict__ scaleshift) {
    int idx = blockIdx.x * 256 + threadIdx.x;
    int base = idx * 4;
    int col = base & 127;
    u16x4 hi = *reinterpret_cast<const u16x4*>(Hh + base);
    u16x4 lo = *reinterpret_cast<const u16x4*>(Hl + base);
#pragma unroll
    for (int j = 0; j < 4; j++) {
        float v = bf2f(hi[j]) + bf2f(lo[j]);
        v = fmaxf(v * scaleshift[col + j] + scaleshift[128 + col + j], 0.f);
        u16 h = f2bf(v);
        hi[j] = h;
        lo[j] = f2bf(v - bf2f(h));
    }
    *reinterpret_cast<u16x4*>(Hh + base) = hi;
    *reinterpret_cast<u16x4*>(Hl + base) = lo;
}

// ---------------- pooling: per-graph range slices (batch sorted) ----------------
__global__ void k_pool(const u16* __restrict__ Hh, const u16* __restrict__ Hl,
                       const int* __restrict__ gs, float* __restrict__ pSum,
                       float* __restrict__ pMax) {
    int g = blockIdx.x >> 3, slice = blockIdx.x & 7;
    int s0 = gs[g], s1 = gs[g + 1];
    int len = s1 - s0;
    int chunk = (len + 7) >> 3;
    int r0 = s0 + slice * chunk;
    int r1 = min(r0 + chunk, s1);
    int t = threadIdx.x;
    int c2 = (t & 63) * 2, half = t >> 6;
    float sa = 0.f, sb = 0.f, ma = 0.f, mb = 0.f;
    for (int r = r0 + half; r < r1; r += 4) {
        u32 h2 = *reinterpret_cast<const u32*>(Hh + r * DIM + c2);
        u32 l2 = *reinterpret_cast<const u32*>(Hl + r * DIM + c2);
        float v0 = __uint_as_float(h2 << 16) + __uint_as_float(l2 << 16);
        float v1 = __uint_as_float(h2 & 0xFFFF0000u) + __uint_as_float(l2 & 0xFFFF0000u);
        sa += v0; sb += v1;
        ma = fmaxf(ma, v0); mb = fmaxf(mb, v1);
    }
    __shared__ float ls[4][128], lm[4][128];
    ls[half][c2] = sa; ls[half][c2 + 1] = sb;
    lm[half][c2] = ma; lm[half][c2 + 1] = mb;
    __syncthreads();
    if (t < 128) {
        float s = ls[0][t] + ls[1][t] + ls[2][t] + ls[3][t];
        float m = fmaxf(fmaxf(lm[0][t], lm[1][t]), fmaxf(lm[2][t], lm[3][t]));
        atomicAdd(&pSum[g * DIM + t], s);
        atomicMax((int*)&pMax[g * DIM + t], __float_as_int(m));  // values >= 0, init 0
    }
}

// ---------------- classifier MLP: one block per graph ----------------
__global__ void k_mlp(const float* __restrict__ pSum, const float* __restrict__ pMax,
                      const int* __restrict__ gs,
                      const float* __restrict__ W1, const float* __restrict__ b1,
                      const float* __restrict__ W2, const float* __restrict__ b2,
                      const float* __restrict__ W3, const float* __restrict__ b3,
                      float* __restrict__ out) {
    __shared__ float g[256], y1[128], y2[64];
    int gi = blockIdx.x;
    int t = threadIdx.x;  // 128 threads
    int cnt = gs[gi + 1] - gs[gi];
    float inv = 1.0f / fmaxf((float)cnt, 1.0f);
    g[t] = pSum[gi * DIM + t] * inv;
    g[128 + t] = pMax[gi * DIM + t];
    __syncthreads();
    float a = b1[t];
    for (int k = 0; k < 256; k++) a += g[k] * W1[k * 128 + t];
    y1[t] = fmaxf(a, 0.f);
    __syncthreads();
    if (t < 64) {
        float a2 = b2[t];
        for (int k = 0; k < 128; k++) a2 += y1[k] * W2[k * 64 + t];
        y2[t] = fmaxf(a2, 0.f);
    }
    __syncthreads();
    if (t < 64) {
        float p = y2[t] * W3[t];
#pragma unroll
        for (int off = 32; off; off >>= 1) p += __shfl_down(p, off);
        if (t == 0) out[gi] = p + b3[0];
    }
}

extern "C" void kernel_launch(void* const* d_in, const int* in_sizes, int n_in,
                              void* d_out, int out_size, void* d_ws, size_t ws_size,
                              hipStream_t stream) {
    const float* x     = (const float*)d_in[0];
    const int*   ei    = (const int*)d_in[1];
    const int*   batch = (const int*)d_in[2];
    const float* Wl    = (const float*)d_in[3];
    const float* bl    = (const float*)d_in[4];
    const float* Wr    = (const float*)d_in[5];
    const float* gamma = (const float*)d_in[6];
    const float* beta  = (const float*)d_in[7];
    const float* W1    = (const float*)d_in[8];
    const float* b1    = (const float*)d_in[9];
    const float* W2    = (const float*)d_in[10];
    const float* b2    = (const float*)d_in[11];
    const float* W3    = (const float*)d_in[12];
    const float* b3    = (const float*)d_in[13];
    float* out = (float*)d_out;

    char* p = (char*)d_ws;
    size_t off = 0;
    auto alloc = [&](size_t bytes) -> void* {
        void* r = p + off;
        off += (bytes + 255) & ~(size_t)255;
        return r;
    };
    const size_t HB = (size_t)NN * DIM * 2;
    u16* Xh   = (u16*)alloc(HB);
    u16* Xl   = (u16*)alloc(HB);
    u16* hAh  = (u16*)alloc(HB);
    u16* hAl  = (u16*)alloc(HB);
    u16* aggh = (u16*)alloc(HB);
    u16* aggl = (u16*)alloc(HB);
    int*   ssrc      = (int*)alloc((size_t)NE * 4);
    u16*   Wth       = (u16*)alloc((size_t)8 * 128 * 256 * 2);
    u16*   Wtl       = (u16*)alloc((size_t)8 * 128 * 256 * 2);
    float* partials  = (float*)alloc((size_t)NBLK * 256 * 4);
    float* colpart   = (float*)alloc(32 * 256 * 4);
    int*   deg       = (int*)alloc(NN * 4);
    float* inv_deg   = (float*)alloc(NN * 4);
    int*   row_start = (int*)alloc((NN + 1) * 4);
    int*   cursor    = (int*)alloc(NN * 4);
    int*   bsum      = (int*)alloc(512 * 4);
    int*   gs        = (int*)alloc((NG + 1) * 4);
    float* scaleshift= (float*)alloc(256 * 4);
    float* pSum      = (float*)alloc(NG * DIM * 4);
    float* pMax      = (float*)alloc(NG * DIM * 4);

    const int nbN = (NN + 255) / 256;
    const int nbE = (NE + 255) / 256;
    const int nbQ = NN * DIM / 4 / 256;  // 12500
    const int aggGrid = (NN + 3) / 4;

    // CSR build + graph bounds
    hipMemsetAsync(deg, 0, NN * 4, stream);
    k_deg_hist<<<nbE, 256, 0, stream>>>(ei, deg);
    k_scan1<<<nbN, 256, 0, stream>>>(deg, row_start, bsum, inv_deg);
    k_scan2<<<1, 512, 0, stream>>>(bsum, nbN);
    k_scan3<<<nbN, 256, 0, stream>>>(row_start, bsum, cursor);
    k_sort<<<nbE, 256, 0, stream>>>(ei, cursor, ssrc);
    k_bounds<<<1, 128, 0, stream>>>(batch, gs);

    // input + weight prep
    k_split_x<<<nbQ, 256, 0, stream>>>(x, Xh, Xl);
    k_prep_w<<<8 * 128 * 256 / 256, 256, 0, stream>>>(Wl, Wr, Wth, Wtl);

    for (int b = 0; b < 4; b++) {
        int c0 = 2 * b, c1 = 2 * b + 1;
        const u16* W0h = Wth + (size_t)c0 * 128 * 256;
        const u16* W0l = Wtl + (size_t)c0 * 128 * 256;
        const u16* W1h = Wth + (size_t)c1 * 128 * 256;
        const u16* W1l = Wtl + (size_t)c1 * 128 * 256;
        k_aggregate<<<aggGrid, 256, 0, stream>>>(Xh, row_start, ssrc, inv_deg, aggh, aggl);
        k_gemm<true, false><<<NBLK, 256, 0, stream>>>(aggh, aggl, Xh, Xl, W0h, W0l,
                                                      bl + c0 * DIM, hAh, hAl, partials);
        k_aggregate<<<aggGrid, 256, 0, stream>>>(hAh, row_start, ssrc, inv_deg, aggh, aggl);
        k_gemm<false, true><<<NBLK, 256, 0, stream>>>(aggh, aggl, hAh, hAl, W1h, W1l,
                                                      bl + c1 * DIM, Xh, Xl, partials);
        k_bn_r1<<<32, 256, 0, stream>>>(partials, colpart);
        k_bn_r2<<<1, 256, 0, stream>>>(colpart, gamma + b * DIM, beta + b * DIM, scaleshift);
        k_bn_apply<<<nbQ, 256, 0, stream>>>(Xh, Xl, scaleshift);
    }

    // pooling + classifier
    hipMemsetAsync(pSum, 0, NG * DIM * 4, stream);
    hipMemsetAsync(pMax, 0, NG * DIM * 4, stream);
    k_pool<<<NG * 8, 256, 0, stream>>>(Xh, Xl, gs, pSum, pMax);
    k_mlp<<<NG, 128, 0, stream>>>(pSum, pMax, gs, W1, b1, W2, b2, W3, b3, out);
}

// Round 5
// 1661.853 us; speedup vs baseline: 2.2570x; 1.0244x over previous
//
#include <hip/hip_runtime.h>
#include <hip/hip_bf16.h>
#include <math.h>

#define NN 100000
#define NE 1600000
#define DIM 128
#define NG 64
#define EPSBN 1e-5f
#define NBLK 782        // (NN+127)/128
#define SORT_WIN 12500  // NN/8 dst-window
#define NBINBLK 6250    // NE/256
#define DSL 64          // slices per window for deg2/scatter

typedef unsigned int u32;
typedef unsigned short u16;
typedef __attribute__((ext_vector_type(8))) short bf8_t;   // 8 x bf16
typedef __attribute__((ext_vector_type(4))) float f4_t;    // 4 x f32
typedef __attribute__((ext_vector_type(4))) unsigned short u16x4;
#define MFMA(a, b, c) __builtin_amdgcn_mfma_f32_16x16x32_bf16((a), (b), (c), 0, 0, 0)

__device__ __forceinline__ u16 f2bf(float f) {
    u32 u = __float_as_uint(f);
    u32 r = u + 0x7FFFu + ((u >> 16) & 1u);   // round-to-nearest-even
    return (u16)(r >> 16);
}
__device__ __forceinline__ float bf2f(u16 h) { return __uint_as_float(((u32)h) << 16); }

// ============ CSR build, XCD-partitioned ============
// Phase 1: deterministic 8-way binning of edges by dst window (no global atomics)
__global__ void k_bin_cnt(const int* __restrict__ ei, int* __restrict__ blkcnt) {
    __shared__ int c[8];
    int t = threadIdx.x;
    if (t < 8) c[t] = 0;
    __syncthreads();
    int e = blockIdx.x * 256 + t;
    int d = ei[NE + e];
    atomicAdd(&c[d / SORT_WIN], 1);
    __syncthreads();
    if (t < 8) blkcnt[blockIdx.x * 8 + t] = c[t];
}

__global__ void k_bin_scan(const int* __restrict__ blkcnt, int* __restrict__ blkoff,
                           int* __restrict__ wtotal) {
    __shared__ int ps[256];
    int w = blockIdx.x, t = threadIdx.x;
    const int PER = (NBINBLK + 255) / 256;  // 25
    int s = 0;
    for (int i = 0; i < PER; ++i) {
        int b = t * PER + i;
        if (b < NBINBLK) s += blkcnt[b * 8 + w];
    }
    ps[t] = s;
    for (int off = 1; off < 256; off <<= 1) {
        __syncthreads();
        int x = (t >= off) ? ps[t - off] : 0;
        __syncthreads();
        ps[t] += x;
    }
    __syncthreads();
    int run = (t ? ps[t - 1] : 0);
    for (int i = 0; i < PER; ++i) {
        int b = t * PER + i;
        if (b < NBINBLK) { blkoff[b * 8 + w] = run; run += blkcnt[b * 8 + w]; }
    }
    if (t == 255) wtotal[w] = ps[255];
}

__global__ void k_bin_start(const int* __restrict__ wtotal, int* __restrict__ binStart) {
    if (threadIdx.x == 0) {
        int a = 0;
        for (int w = 0; w < 8; ++w) { binStart[w] = a; a += wtotal[w]; }
        binStart[8] = a;
    }
}

__global__ void k_bin_place(const int* __restrict__ ei, const int* __restrict__ blkoff,
                            const int* __restrict__ binStart, int2* __restrict__ binned) {
    __shared__ int base[8];
    int t = threadIdx.x;
    if (t < 8) base[t] = binStart[t] + blkoff[blockIdx.x * 8 + t];
    __syncthreads();
    int e = blockIdx.x * 256 + t;
    int s = ei[e], d = ei[NE + e];
    int pos = atomicAdd(&base[d / SORT_WIN], 1);
    binned[pos] = make_int2(s, d);
}

// Phase 2: XCD-local deg hist + scatter (window = blockIdx%8 -> one XCD owns its lines)
__global__ void k_deg2(const int2* __restrict__ binned, const int* __restrict__ binStart,
                       int* __restrict__ deg) {
    int w = blockIdx.x & 7, sl = blockIdx.x >> 3;
    int b0 = binStart[w], b1 = binStart[w + 1];
    int chunk = (b1 - b0 + DSL - 1) / DSL;
    int r0 = b0 + sl * chunk, r1 = min(r0 + chunk, b1);
    for (int i = r0 + threadIdx.x; i < r1; i += 256)
        atomicAdd(&deg[binned[i].y], 1);
}

__global__ void k_scatter(const int2* __restrict__ binned, const int* __restrict__ binStart,
                          int* __restrict__ cursor, int* __restrict__ sorted_src) {
    int w = blockIdx.x & 7, sl = blockIdx.x >> 3;
    int b0 = binStart[w], b1 = binStart[w + 1];
    int chunk = (b1 - b0 + DSL - 1) / DSL;
    int r0 = b0 + sl * chunk, r1 = min(r0 + chunk, b1);
    for (int i = r0 + threadIdx.x; i < r1; i += 256) {
        int2 e = binned[i];
        int pos = atomicAdd(&cursor[e.y], 1);
        sorted_src[pos] = e.x;
    }
}

#define SCAN_B 256
__global__ void k_scan1(const int* __restrict__ deg, int* __restrict__ row_start,
                        int* __restrict__ bsum, float* __restrict__ inv_deg) {
    __shared__ int s[SCAN_B];
    int t = threadIdx.x;
    int i = blockIdx.x * SCAN_B + t;
    int v = (i < NN) ? deg[i] : 0;
    if (i < NN) inv_deg[i] = 1.0f / (float)(v > 1 ? v : 1);
    s[t] = v;
    for (int off = 1; off < SCAN_B; off <<= 1) {
        __syncthreads();
        int x = (t >= off) ? s[t - off] : 0;
        __syncthreads();
        s[t] += x;
    }
    if (i < NN) row_start[i + 1] = s[t];
    if (t == SCAN_B - 1) bsum[blockIdx.x] = s[t];
}

__global__ void k_scan2(int* __restrict__ bsum, int nb) {
    __shared__ int s[512];
    int t = threadIdx.x;
    int v = (t < nb) ? bsum[t] : 0;
    s[t] = v;
    for (int off = 1; off < 512; off <<= 1) {
        __syncthreads();
        int x = (t >= off) ? s[t - off] : 0;
        __syncthreads();
        s[t] += x;
    }
    if (t < nb) bsum[t] = s[t] - v;
}

__global__ void k_scan3(int* __restrict__ row_start, const int* __restrict__ bsum,
                        int* __restrict__ cursor) {
    int i = blockIdx.x * blockDim.x + threadIdx.x;
    if (i < NN) {
        int v = row_start[i + 1] + bsum[i / SCAN_B];
        row_start[i + 1] = v;
        if (i + 1 < NN) cursor[i + 1] = v;
    }
    if (i == 0) { row_start[0] = 0; cursor[0] = 0; }
}

// graph ranges via binary search (batch is sorted)
__global__ void k_bounds(const int* __restrict__ batch, int* __restrict__ gs) {
    int g = threadIdx.x;
    if (g > NG) return;
    int lo = 0, hi = NN;
    while (lo < hi) {
        int mid = (lo + hi) >> 1;
        if (batch[mid] < g) lo = mid + 1; else hi = mid;
    }
    gs[g] = lo;
}

// ---------------- fp32 x -> split bf16 (hi, lo) ----------------
__global__ void k_split_x(const float* __restrict__ x, u16* __restrict__ Xh,
                          u16* __restrict__ Xl) {
    int idx = blockIdx.x * 256 + threadIdx.x;
    int base = idx * 4;
    float4 v = *reinterpret_cast<const float4*>(&x[base]);
    u16x4 hi, lo;
    float vv[4] = {v.x, v.y, v.z, v.w};
#pragma unroll
    for (int j = 0; j < 4; j++) {
        u16 h = f2bf(vv[j]);
        hi[j] = h;
        lo[j] = f2bf(vv[j] - bf2f(h));
    }
    *reinterpret_cast<u16x4*>(&Xh[base]) = hi;
    *reinterpret_cast<u16x4*>(&Xl[base]) = lo;
}

// ---------------- weight prep: transpose+stack+split ----------------
__global__ void k_prep_w(const float* __restrict__ Wl, const float* __restrict__ Wr,
                         u16* __restrict__ Wth, u16* __restrict__ Wtl) {
    int idx = blockIdx.x * 256 + threadIdx.x;  // 8*128*256
    int k = idx & 255;
    int col = (idx >> 8) & 127;
    int c = idx >> 15;
    float v = (k < 128) ? Wl[(c * 128 + k) * 128 + col] : Wr[(c * 128 + (k - 128)) * 128 + col];
    u16 h = f2bf(v);
    Wth[idx] = h;
    Wtl[idx] = f2bf(v - bf2f(h));
}

// ---------------- mean aggregation: hi-only gather; optional fused BN+relu -----
template <int AFF>
__global__ void k_aggregate(const u16* __restrict__ Hh,
                            const int* __restrict__ row_start, const int* __restrict__ ssrc,
                            const float* __restrict__ inv_deg, const float* __restrict__ ss,
                            u16* __restrict__ Ah, u16* __restrict__ Al) {
    int wid = blockIdx.x * 4 + (threadIdx.x >> 6);
    int lane = threadIdx.x & 63;
    int half = lane >> 5;
    int cl = lane & 31;     // cols [cl*4, cl*4+4)
    if (wid >= NN) return;
    float sc0 = 0.f, sc1 = 0.f, sc2 = 0.f, sc3 = 0.f;
    float sh0 = 0.f, sh1 = 0.f, sh2 = 0.f, sh3 = 0.f;
    if (AFF) {
        float4 s4 = *reinterpret_cast<const float4*>(ss + cl * 4);
        float4 h4 = *reinterpret_cast<const float4*>(ss + 128 + cl * 4);
        sc0 = s4.x; sc1 = s4.y; sc2 = s4.z; sc3 = s4.w;
        sh0 = h4.x; sh1 = h4.y; sh2 = h4.z; sh3 = h4.w;
    }
    int beg = row_start[wid], end = row_start[wid + 1];
    int n = end - beg;
    float a0 = 0.f, a1 = 0.f, a2 = 0.f, a3 = 0.f;
#define ACCUM(vv)                                                                   \
    {                                                                               \
        float t0 = __uint_as_float((vv).x << 16);                                   \
        float t1 = __uint_as_float((vv).x & 0xFFFF0000u);                           \
        float t2 = __uint_as_float((vv).y << 16);                                   \
        float t3 = __uint_as_float((vv).y & 0xFFFF0000u);                           \
        if (AFF) {                                                                  \
            t0 = fmaxf(t0 * sc0 + sh0, 0.f); t1 = fmaxf(t1 * sc1 + sh1, 0.f);       \
            t2 = fmaxf(t2 * sc2 + sh2, 0.f); t3 = fmaxf(t3 * sc3 + sh3, 0.f);       \
        }                                                                           \
        a0 += t0; a1 += t1; a2 += t2; a3 += t3;                                     \
    }
    for (int base = 0; base < n; base += 64) {
        int rem = n - base;
        int idx = beg + base + (lane < rem ? lane : 0);
        int sv = ssrc[idx];
        int m = rem < 64 ? rem : 64;
        int j = 0;
        for (; j + 4 <= m; j += 4) {
            int sA = __shfl(sv, j + half);
            int sB = __shfl(sv, j + 2 + half);
            uint2 vA = *reinterpret_cast<const uint2*>(
                reinterpret_cast<const u32*>(Hh + (size_t)sA * DIM) + cl * 2);
            uint2 vB = *reinterpret_cast<const uint2*>(
                reinterpret_cast<const u32*>(Hh + (size_t)sB * DIM) + cl * 2);
            ACCUM(vA); ACCUM(vB);
        }
        for (; j < m; j += 2) {
            if (j + half < m) {
                int s0 = __shfl(sv, j + half);
                uint2 v = *reinterpret_cast<const uint2*>(
                    reinterpret_cast<const u32*>(Hh + (size_t)s0 * DIM) + cl * 2);
                ACCUM(v);
            }
        }
    }
#undef ACCUM
    a0 += __shfl_down(a0, 32);
    a1 += __shfl_down(a1, 32);
    a2 += __shfl_down(a2, 32);
    a3 += __shfl_down(a3, 32);
    if (half == 0) {
        float sc = inv_deg[wid];
        a0 *= sc; a1 *= sc; a2 *= sc; a3 *= sc;
        u16 h0 = f2bf(a0), h1 = f2bf(a1), h2 = f2bf(a2), h3 = f2bf(a3);
        u16 l0 = f2bf(a0 - bf2f(h0)), l1 = f2bf(a1 - bf2f(h1));
        u16 l2 = f2bf(a2 - bf2f(h2)), l3 = f2bf(a3 - bf2f(h3));
        uint2 hv = make_uint2((u32)h0 | ((u32)h1 << 16), (u32)h2 | ((u32)h3 << 16));
        uint2 lv = make_uint2((u32)l0 | ((u32)l1 << 16), (u32)l2 | ((u32)l3 << 16));
        *reinterpret_cast<uint2*>(Ah + (size_t)wid * DIM + cl * 4) = hv;
        *reinterpret_cast<uint2*>(Al + (size_t)wid * DIM + cl * 4) = lv;
    }
}

// in-register: v = relu(affine(hi+lo)); re-split
__device__ __forceinline__ void affine_split(bf8_t& h, bf8_t& l,
                                             const float* __restrict__ ss, int k0) {
#pragma unroll
    for (int j = 0; j < 8; ++j) {
        float v = bf2f((u16)h[j]) + bf2f((u16)l[j]);
        v = fmaxf(v * ss[k0 + j] + ss[128 + k0 + j], 0.f);
        u16 hh = f2bf(v);
        h[j] = (short)hh;
        l[j] = (short)f2bf(v - bf2f(hh));
    }
}

// ---------------- fused conv GEMM (MFMA, split-bf16 = fp32-accurate) ---------
// AFF2: apply relu(affine(.)) to A2 (pre-BN h) in registers
template <bool RELU, bool STATS, bool AFF2>
__global__ __launch_bounds__(256) void k_gemm(
    const u16* __restrict__ A1h, const u16* __restrict__ A1l,
    const u16* __restrict__ A2h, const u16* __restrict__ A2l,
    const u16* __restrict__ Wth, const u16* __restrict__ Wtl,
    const float* __restrict__ bias, const float* __restrict__ ss,
    u16* __restrict__ Oh, u16* __restrict__ Ol,
    float* __restrict__ partials) {
    __shared__ float cs[128], cq[128];
    int t = threadIdx.x;
    if (STATS) {
        if (t < 128) { cs[t] = 0.f; cq[t] = 0.f; }
        __syncthreads();
    }
    int w = t >> 6, l = t & 63;
    int rl = l & 15, kg = l >> 4;
    int rbase = blockIdx.x * 128 + w * 32;
    int row0 = rbase + rl, row1 = rbase + 16 + rl;
    int row0c = min(row0, NN - 1), row1c = min(row1, NN - 1);

    f4_t acc[2][8];
#pragma unroll
    for (int i = 0; i < 2; i++)
#pragma unroll
        for (int j = 0; j < 8; j++) acc[i][j] = (f4_t){0.f, 0.f, 0.f, 0.f};

#pragma unroll
    for (int ks = 0; ks < 4; ++ks) {  // K half 1: A1 (agg)
        int k0 = ks * 32 + kg * 8;
        bf8_t a0h = *reinterpret_cast<const bf8_t*>(A1h + row0c * DIM + k0);
        bf8_t a0l = *reinterpret_cast<const bf8_t*>(A1l + row0c * DIM + k0);
        bf8_t a1h = *reinterpret_cast<const bf8_t*>(A1h + row1c * DIM + k0);
        bf8_t a1l = *reinterpret_cast<const bf8_t*>(A1l + row1c * DIM + k0);
#pragma unroll
        for (int cf = 0; cf < 8; ++cf) {
            int wo = (cf * 16 + rl) * 256 + k0;
            bf8_t bh = *reinterpret_cast<const bf8_t*>(Wth + wo);
            bf8_t bl_ = *reinterpret_cast<const bf8_t*>(Wtl + wo);
            acc[0][cf] = MFMA(a0h, bh, acc[0][cf]);
            acc[0][cf] = MFMA(a0h, bl_, acc[0][cf]);
            acc[0][cf] = MFMA(a0l, bh, acc[0][cf]);
            acc[1][cf] = MFMA(a1h, bh, acc[1][cf]);
            acc[1][cf] = MFMA(a1h, bl_, acc[1][cf]);
            acc[1][cf] = MFMA(a1l, bh, acc[1][cf]);
        }
    }
#pragma unroll
    for (int ks = 0; ks < 4; ++ks) {  // K half 2: A2 (h)
        int k0 = ks * 32 + kg * 8;
        bf8_t a0h = *reinterpret_cast<const bf8_t*>(A2h + row0c * DIM + k0);
        bf8_t a0l = *reinterpret_cast<const bf8_t*>(A2l + row0c * DIM + k0);
        bf8_t a1h = *reinterpret_cast<const bf8_t*>(A2h + row1c * DIM + k0);
        bf8_t a1l = *reinterpret_cast<const bf8_t*>(A2l + row1c * DIM + k0);
        if (AFF2) {
            affine_split(a0h, a0l, ss, k0);
            affine_split(a1h, a1l, ss, k0);
        }
#pragma unroll
        for (int cf = 0; cf < 8; ++cf) {
            int wo = (cf * 16 + rl) * 256 + 128 + k0;
            bf8_t bh = *reinterpret_cast<const bf8_t*>(Wth + wo);
            bf8_t bl_ = *reinterpret_cast<const bf8_t*>(Wtl + wo);
            acc[0][cf] = MFMA(a0h, bh, acc[0][cf]);
            acc[0][cf] = MFMA(a0h, bl_, acc[0][cf]);
            acc[0][cf] = MFMA(a0l, bh, acc[0][cf]);
            acc[1][cf] = MFMA(a1h, bh, acc[1][cf]);
            acc[1][cf] = MFMA(a1h, bl_, acc[1][cf]);
            acc[1][cf] = MFMA(a1l, bh, acc[1][cf]);
        }
    }

    // epilogue: C/D layout col = lane&15, row = (lane>>4)*4 + i  [verified m89]
#pragma unroll
    for (int rf = 0; rf < 2; ++rf) {
        int rb = rbase + rf * 16 + kg * 4;
#pragma unroll
        for (int cf = 0; cf < 8; ++cf) {
            int col = cf * 16 + rl;
            float bv = bias[col];
            float s = 0.f, q = 0.f;
#pragma unroll
            for (int i = 0; i < 4; ++i) {
                int row = rb + i;
                float v = acc[rf][cf][i] + bv;
                if (RELU) v = fmaxf(v, 0.f);
                if (row < NN) {
                    u16 hi = f2bf(v);
                    Oh[row * DIM + col] = hi;
                    Ol[row * DIM + col] = f2bf(v - bf2f(hi));
                    if (STATS) { s += v; q += v * v; }
                }
            }
            if (STATS) {
                s += __shfl_xor(s, 16); s += __shfl_xor(s, 32);
                q += __shfl_xor(q, 16); q += __shfl_xor(q, 32);
                if (l < 16) {
                    atomicAdd(&cs[col], s);
                    atomicAdd(&cq[col], q);
                }
            }
        }
    }
    if (STATS) {
        __syncthreads();
        partials[blockIdx.x * 256 + t] = (t < 128) ? cs[t] : cq[t - 128];
    }
}

// ---------------- BN: two-stage parallel reduce -> scale/shift ----------------
__global__ void k_bn_r1(const float* __restrict__ partials, float* __restrict__ colpart) {
    int t = threadIdx.x;
    int b = blockIdx.x;  // 32 blocks
    int b0 = b * 25, b1 = min(b0 + 25, NBLK);
    float s = 0.f;
    for (int i = b0; i < b1; ++i) s += partials[i * 256 + t];
    colpart[b * 256 + t] = s;
}

__global__ void k_bn_r2(const float* __restrict__ colpart, const float* __restrict__ gamma,
                        const float* __restrict__ beta, float* __restrict__ scaleshift) {
    __shared__ float sm[256];
    int t = threadIdx.x;
    float s = 0.f;
#pragma unroll
    for (int b = 0; b < 32; ++b) s += colpart[b * 256 + t];
    sm[t] = s;
    __syncthreads();
    if (t < 128) {
        float mu = sm[t] * (1.0f / NN);
        float var = sm[t + 128] * (1.0f / NN) - mu * mu;
        float sc = rsqrtf(var + EPSBN) * gamma[t];
        scaleshift[t] = sc;
        scaleshift[t + 128] = beta[t] - mu * sc;
    }
}

// ---------------- pooling: hi-only + fused BN+relu ----------------
__global__ void k_pool(const u16* __restrict__ Hh, const int* __restrict__ gs,
                       const float* __restrict__ ss,
                       float* __restrict__ pSum, float* __restrict__ pMax) {
    int g = blockIdx.x >> 3, slice = blockIdx.x & 7;
    int s0 = gs[g], s1 = gs[g + 1];
    int len = s1 - s0;
    int chunk = (len + 7) >> 3;
    int r0 = s0 + slice * chunk;
    int r1 = min(r0 + chunk, s1);
    int t = threadIdx.x;
    int c2 = (t & 63) * 2, half = t >> 6;
    float sc0 = ss[c2], sc1 = ss[c2 + 1];
    float sh0 = ss[128 + c2], sh1 = ss[128 + c2 + 1];
    float sa = 0.f, sb = 0.f, ma = 0.f, mb = 0.f;
    for (int r = r0 + half; r < r1; r += 4) {
        u32 h2 = *reinterpret_cast<const u32*>(Hh + r * DIM + c2);
        float v0 = fmaxf(__uint_as_float(h2 << 16) * sc0 + sh0, 0.f);
        float v1 = fmaxf(__uint_as_float(h2 & 0xFFFF0000u) * sc1 + sh1, 0.f);
        sa += v0; sb += v1;
        ma = fmaxf(ma, v0); mb = fmaxf(mb, v1);
    }
    __shared__ float ls[4][128], lm[4][128];
    ls[half][c2] = sa; ls[half][c2 + 1] = sb;
    lm[half][c2] = ma; lm[half][c2 + 1] = mb;
    __syncthreads();
    if (t < 128) {
        float s = ls[0][t] + ls[1][t] + ls[2][t] + ls[3][t];
        float m = fmaxf(fmaxf(lm[0][t], lm[1][t]), fmaxf(lm[2][t], lm[3][t]));
        atomicAdd(&pSum[g * DIM + t], s);
        atomicMax((int*)&pMax[g * DIM + t], __float_as_int(m));  // values >= 0, init 0
    }
}

// ---------------- classifier MLP: one block per graph ----------------
__global__ void k_mlp(const float* __restrict__ pSum, const float* __restrict__ pMax,
                      const int* __restrict__ gs,
                      const float* __restrict__ W1, const float* __restrict__ b1,
                      const float* __restrict__ W2, const float* __restrict__ b2,
                      const float* __restrict__ W3, const float* __restrict__ b3,
                      float* __restrict__ out) {
    __shared__ float g[256], y1[128], y2[64];
    int gi = blockIdx.x;
    int t = threadIdx.x;  // 128 threads
    int cnt = gs[gi + 1] - gs[gi];
    float inv = 1.0f / fmaxf((float)cnt, 1.0f);
    g[t] = pSum[gi * DIM + t] * inv;
    g[128 + t] = pMax[gi * DIM + t];
    __syncthreads();
    float a = b1[t];
    for (int k = 0; k < 256; k++) a += g[k] * W1[k * 128 + t];
    y1[t] = fmaxf(a, 0.f);
    __syncthreads();
    if (t < 64) {
        float a2 = b2[t];
        for (int k = 0; k < 128; k++) a2 += y1[k] * W2[k * 64 + t];
        y2[t] = fmaxf(a2, 0.f);
    }
    __syncthreads();
    if (t < 64) {
        float p = y2[t] * W3[t];
#pragma unroll
        for (int off = 32; off; off >>= 1) p += __shfl_down(p, off);
        if (t == 0) out[gi] = p + b3[0];
    }
}

extern "C" void kernel_launch(void* const* d_in, const int* in_sizes, int n_in,
                              void* d_out, int out_size, void* d_ws, size_t ws_size,
                              hipStream_t stream) {
    const float* x     = (const float*)d_in[0];
    const int*   ei    = (const int*)d_in[1];
    const int*   batch = (const int*)d_in[2];
    const float* Wl    = (const float*)d_in[3];
    const float* bl    = (const float*)d_in[4];
    const float* Wr    = (const float*)d_in[5];
    const float* gamma = (const float*)d_in[6];
    const float* beta  = (const float*)d_in[7];
    const float* W1    = (const float*)d_in[8];
    const float* b1    = (const float*)d_in[9];
    const float* W2    = (const float*)d_in[10];
    const float* b2    = (const float*)d_in[11];
    const float* W3    = (const float*)d_in[12];
    const float* b3    = (const float*)d_in[13];
    float* out = (float*)d_out;

    char* p = (char*)d_ws;
    size_t off = 0;
    auto alloc = [&](size_t bytes) -> void* {
        void* r = p + off;
        off += (bytes + 255) & ~(size_t)255;
        return r;
    };
    const size_t HB = (size_t)NN * DIM * 2;
    u16* Xh   = (u16*)alloc(HB);   // block input / conv2 output (pre-BN), ping-pong
    u16* Xl   = (u16*)alloc(HB);
    u16* hAh  = (u16*)alloc(HB);
    u16* hAl  = (u16*)alloc(HB);
    u16* aggh = (u16*)alloc(HB);   // also aliases `binned` during CSR build
    u16* aggl = (u16*)alloc(HB);
    int*   ssrc      = (int*)alloc((size_t)NE * 4);
    u16*   Wth       = (u16*)alloc((size_t)8 * 128 * 256 * 2);
    u16*   Wtl       = (u16*)alloc((size_t)8 * 128 * 256 * 2);
    float* partials  = (float*)alloc((size_t)NBLK * 256 * 4);
    float* colpart   = (float*)alloc(32 * 256 * 4);
    int*   deg       = (int*)alloc(NN * 4);
    float* inv_deg   = (float*)alloc(NN * 4);
    int*   row_start = (int*)alloc((NN + 1) * 4);
    int*   cursor    = (int*)alloc(NN * 4);
    int*   bsum      = (int*)alloc(512 * 4);
    int*   gs        = (int*)alloc((NG + 1) * 4);
    int*   blkcnt    = (int*)alloc((size_t)NBINBLK * 8 * 4);
    int*   blkoff    = (int*)alloc((size_t)NBINBLK * 8 * 4);
    int*   wtotal    = (int*)alloc(8 * 4);
    int*   binStart  = (int*)alloc(9 * 4);
    float* ssb       = (float*)alloc(4 * 256 * 4);   // per-block scale/shift
    float* pSum      = (float*)alloc(NG * DIM * 4);
    float* pMax      = (float*)alloc(NG * DIM * 4);
    int2*  binned    = (int2*)aggh;  // 12.8MB, dead before first k_aggregate write

    const int nbN = (NN + 255) / 256;
    const int nbQ = NN * DIM / 4 / 256;  // 12500
    const int aggGrid = (NN + 3) / 4;

    // ---- CSR build (XCD-partitioned) ----
    hipMemsetAsync(deg, 0, NN * 4, stream);
    k_bin_cnt<<<NBINBLK, 256, 0, stream>>>(ei, blkcnt);
    k_bin_scan<<<8, 256, 0, stream>>>(blkcnt, blkoff, wtotal);
    k_bin_start<<<1, 64, 0, stream>>>(wtotal, binStart);
    k_bin_place<<<NBINBLK, 256, 0, stream>>>(ei, blkoff, binStart, binned);
    k_deg2<<<8 * DSL, 256, 0, stream>>>(binned, binStart, deg);
    k_scan1<<<nbN, 256, 0, stream>>>(deg, row_start, bsum, inv_deg);
    k_scan2<<<1, 512, 0, stream>>>(bsum, nbN);
    k_scan3<<<nbN, 256, 0, stream>>>(row_start, bsum, cursor);
    k_scatter<<<8 * DSL, 256, 0, stream>>>(binned, binStart, cursor, ssrc);
    k_bounds<<<1, 128, 0, stream>>>(batch, gs);

    // ---- input + weight prep ----
    k_split_x<<<nbQ, 256, 0, stream>>>(x, Xh, Xl);
    k_prep_w<<<8 * 128 * 256 / 256, 256, 0, stream>>>(Wl, Wr, Wth, Wtl);

    for (int b = 0; b < 4; b++) {
        int c0 = 2 * b, c1 = 2 * b + 1;
        const u16* W0h = Wth + (size_t)c0 * 128 * 256;
        const u16* W0l = Wtl + (size_t)c0 * 128 * 256;
        const u16* W1h = Wth + (size_t)c1 * 128 * 256;
        const u16* W1l = Wtl + (size_t)c1 * 128 * 256;
        const float* ssPrev = ssb + (size_t)(b > 0 ? b - 1 : 0) * 256;
        // agg1 + conv1 (input transform = relu∘affine for b>0, identity for b=0)
        if (b == 0) {
            k_aggregate<0><<<aggGrid, 256, 0, stream>>>(Xh, row_start, ssrc, inv_deg,
                                                        ssPrev, aggh, aggl);
            k_gemm<true, false, false><<<NBLK, 256, 0, stream>>>(
                aggh, aggl, Xh, Xl, W0h, W0l, bl + c0 * DIM, ssPrev, hAh, hAl, partials);
        } else {
            k_aggregate<1><<<aggGrid, 256, 0, stream>>>(Xh, row_start, ssrc, inv_deg,
                                                        ssPrev, aggh, aggl);
            k_gemm<true, false, true><<<NBLK, 256, 0, stream>>>(
                aggh, aggl, Xh, Xl, W0h, W0l, bl + c0 * DIM, ssPrev, hAh, hAl, partials);
        }
        // agg2 + conv2 (+stats); output pre-BN into Xh/Xl
        k_aggregate<0><<<aggGrid, 256, 0, stream>>>(hAh, row_start, ssrc, inv_deg,
                                                    ssPrev, aggh, aggl);
        k_gemm<false, true, false><<<NBLK, 256, 0, stream>>>(
            aggh, aggl, hAh, hAl, W1h, W1l, bl + c1 * DIM, ssPrev, Xh, Xl, partials);
        k_bn_r1<<<32, 256, 0, stream>>>(partials, colpart);
        k_bn_r2<<<1, 256, 0, stream>>>(colpart, gamma + b * DIM, beta + b * DIM,
                                       ssb + (size_t)b * 256);
    }

    // ---- pooling (fused BN+relu) + classifier ----
    hipMemsetAsync(pSum, 0, NG * DIM * 4, stream);
    hipMemsetAsync(pMax, 0, NG * DIM * 4, stream);
    k_pool<<<NG * 8, 256, 0, stream>>>(Xh, gs, ssb + 3 * 256, pSum, pMax);
    k_mlp<<<NG, 128, 0, stream>>>(pSum, pMax, gs, W1, b1, W2, b2, W3, b3, out);
}

// Round 6
// 1645.788 us; speedup vs baseline: 2.2790x; 1.0098x over previous
//
#include <hip/hip_runtime.h>
#include <hip/hip_bf16.h>
#include <math.h>

#define NN 100000
#define NE 1600000
#define DIM 128
#define NG 64
#define EPSBN 1e-5f
#define NGB 1563        // (NN+63)/64 gemm tiles
#define SORT_WIN 12500  // NN/8 dst-window
#define NBINBLK 6250    // NE/256
#define DSL 64          // slices per window for deg2/scatter

typedef unsigned int u32;
typedef unsigned short u16;
typedef __attribute__((ext_vector_type(8))) short bf8_t;   // 8 x bf16
typedef __attribute__((ext_vector_type(4))) float f4_t;    // 4 x f32
typedef __attribute__((ext_vector_type(4))) unsigned short u16x4;
#define MFMA(a, b, c) __builtin_amdgcn_mfma_f32_16x16x32_bf16((a), (b), (c), 0, 0, 0)

__device__ __forceinline__ u16 f2bf(float f) {
    u32 u = __float_as_uint(f);
    u32 r = u + 0x7FFFu + ((u >> 16) & 1u);   // round-to-nearest-even
    return (u16)(r >> 16);
}
__device__ __forceinline__ float bf2f(u16 h) { return __uint_as_float(((u32)h) << 16); }

// ============ CSR build, XCD-partitioned ============
__global__ void k_bin_cnt(const int* __restrict__ ei, int* __restrict__ blkcnt) {
    __shared__ int c[8];
    int t = threadIdx.x;
    if (t < 8) c[t] = 0;
    __syncthreads();
    int e = blockIdx.x * 256 + t;
    int d = ei[NE + e];
    atomicAdd(&c[d / SORT_WIN], 1);
    __syncthreads();
    if (t < 8) blkcnt[blockIdx.x * 8 + t] = c[t];
}

__global__ void k_bin_scan(const int* __restrict__ blkcnt, int* __restrict__ blkoff,
                           int* __restrict__ wtotal) {
    __shared__ int ps[256];
    int w = blockIdx.x, t = threadIdx.x;
    const int PER = (NBINBLK + 255) / 256;  // 25
    int s = 0;
    for (int i = 0; i < PER; ++i) {
        int b = t * PER + i;
        if (b < NBINBLK) s += blkcnt[b * 8 + w];
    }
    ps[t] = s;
    for (int off = 1; off < 256; off <<= 1) {
        __syncthreads();
        int x = (t >= off) ? ps[t - off] : 0;
        __syncthreads();
        ps[t] += x;
    }
    __syncthreads();
    int run = (t ? ps[t - 1] : 0);
    for (int i = 0; i < PER; ++i) {
        int b = t * PER + i;
        if (b < NBINBLK) { blkoff[b * 8 + w] = run; run += blkcnt[b * 8 + w]; }
    }
    if (t == 255) wtotal[w] = ps[255];
}

__global__ void k_bin_start(const int* __restrict__ wtotal, int* __restrict__ binStart) {
    if (threadIdx.x == 0) {
        int a = 0;
        for (int w = 0; w < 8; ++w) { binStart[w] = a; a += wtotal[w]; }
        binStart[8] = a;
    }
}

__global__ void k_bin_place(const int* __restrict__ ei, const int* __restrict__ blkoff,
                            const int* __restrict__ binStart, int2* __restrict__ binned) {
    __shared__ int base[8];
    int t = threadIdx.x;
    if (t < 8) base[t] = binStart[t] + blkoff[blockIdx.x * 8 + t];
    __syncthreads();
    int e = blockIdx.x * 256 + t;
    int s = ei[e], d = ei[NE + e];
    int pos = atomicAdd(&base[d / SORT_WIN], 1);
    binned[pos] = make_int2(s, d);
}

__global__ void k_deg2(const int2* __restrict__ binned, const int* __restrict__ binStart,
                       int* __restrict__ deg) {
    int w = blockIdx.x & 7, sl = blockIdx.x >> 3;
    int b0 = binStart[w], b1 = binStart[w + 1];
    int chunk = (b1 - b0 + DSL - 1) / DSL;
    int r0 = b0 + sl * chunk, r1 = min(r0 + chunk, b1);
    for (int i = r0 + threadIdx.x; i < r1; i += 256)
        atomicAdd(&deg[binned[i].y], 1);
}

__global__ void k_scatter(const int2* __restrict__ binned, const int* __restrict__ binStart,
                          int* __restrict__ cursor, int* __restrict__ sorted_src) {
    int w = blockIdx.x & 7, sl = blockIdx.x >> 3;
    int b0 = binStart[w], b1 = binStart[w + 1];
    int chunk = (b1 - b0 + DSL - 1) / DSL;
    int r0 = b0 + sl * chunk, r1 = min(r0 + chunk, b1);
    for (int i = r0 + threadIdx.x; i < r1; i += 256) {
        int2 e = binned[i];
        int pos = atomicAdd(&cursor[e.y], 1);
        sorted_src[pos] = e.x;
    }
}

#define SCAN_B 256
__global__ void k_scan1(const int* __restrict__ deg, int* __restrict__ row_start,
                        int* __restrict__ bsum, float* __restrict__ inv_deg) {
    __shared__ int s[SCAN_B];
    int t = threadIdx.x;
    int i = blockIdx.x * SCAN_B + t;
    int v = (i < NN) ? deg[i] : 0;
    if (i < NN) inv_deg[i] = 1.0f / (float)(v > 1 ? v : 1);
    s[t] = v;
    for (int off = 1; off < SCAN_B; off <<= 1) {
        __syncthreads();
        int x = (t >= off) ? s[t - off] : 0;
        __syncthreads();
        s[t] += x;
    }
    if (i < NN) row_start[i + 1] = s[t];
    if (t == SCAN_B - 1) bsum[blockIdx.x] = s[t];
}

__global__ void k_scan2(int* __restrict__ bsum, int nb) {
    __shared__ int s[512];
    int t = threadIdx.x;
    int v = (t < nb) ? bsum[t] : 0;
    s[t] = v;
    for (int off = 1; off < 512; off <<= 1) {
        __syncthreads();
        int x = (t >= off) ? s[t - off] : 0;
        __syncthreads();
        s[t] += x;
    }
    if (t < nb) bsum[t] = s[t] - v;
}

__global__ void k_scan3(int* __restrict__ row_start, const int* __restrict__ bsum,
                        int* __restrict__ cursor) {
    int i = blockIdx.x * blockDim.x + threadIdx.x;
    if (i < NN) {
        int v = row_start[i + 1] + bsum[i / SCAN_B];
        row_start[i + 1] = v;
        if (i + 1 < NN) cursor[i + 1] = v;
    }
    if (i == 0) { row_start[0] = 0; cursor[0] = 0; }
}

__global__ void k_bounds(const int* __restrict__ batch, int* __restrict__ gs) {
    int g = threadIdx.x;
    if (g > NG) return;
    int lo = 0, hi = NN;
    while (lo < hi) {
        int mid = (lo + hi) >> 1;
        if (batch[mid] < g) lo = mid + 1; else hi = mid;
    }
    gs[g] = lo;
}

// ---------------- fp32 x -> split bf16 (hi, lo) ----------------
__global__ void k_split_x(const float* __restrict__ x, u16* __restrict__ Xh,
                          u16* __restrict__ Xl) {
    int idx = blockIdx.x * 256 + threadIdx.x;
    int base = idx * 4;
    float4 v = *reinterpret_cast<const float4*>(&x[base]);
    u16x4 hi, lo;
    float vv[4] = {v.x, v.y, v.z, v.w};
#pragma unroll
    for (int j = 0; j < 4; j++) {
        u16 h = f2bf(vv[j]);
        hi[j] = h;
        lo[j] = f2bf(vv[j] - bf2f(h));
    }
    *reinterpret_cast<u16x4*>(&Xh[base]) = hi;
    *reinterpret_cast<u16x4*>(&Xl[base]) = lo;
}

// ---------------- weight prep: transpose+stack+split ----------------
__global__ void k_prep_w(const float* __restrict__ Wl, const float* __restrict__ Wr,
                         u16* __restrict__ Wth, u16* __restrict__ Wtl) {
    int idx = blockIdx.x * 256 + threadIdx.x;  // 8*128*256
    int k = idx & 255;
    int col = (idx >> 8) & 127;
    int c = idx >> 15;
    float v = (k < 128) ? Wl[(c * 128 + k) * 128 + col] : Wr[(c * 128 + (k - 128)) * 128 + col];
    u16 h = f2bf(v);
    Wth[idx] = h;
    Wtl[idx] = f2bf(v - bf2f(h));
}

// ---------------- mean aggregation: hi-only gather; optional fused BN+relu -----
template <int AFF>
__global__ void k_aggregate(const u16* __restrict__ Hh,
                            const int* __restrict__ row_start, const int* __restrict__ ssrc,
                            const float* __restrict__ inv_deg, const float* __restrict__ ss,
                            u16* __restrict__ Ah, u16* __restrict__ Al) {
    int wid = blockIdx.x * 4 + (threadIdx.x >> 6);
    int lane = threadIdx.x & 63;
    int half = lane >> 5;
    int cl = lane & 31;     // cols [cl*4, cl*4+4)
    if (wid >= NN) return;
    float sc0 = 0.f, sc1 = 0.f, sc2 = 0.f, sc3 = 0.f;
    float sh0 = 0.f, sh1 = 0.f, sh2 = 0.f, sh3 = 0.f;
    if (AFF) {
        float4 s4 = *reinterpret_cast<const float4*>(ss + cl * 4);
        float4 h4 = *reinterpret_cast<const float4*>(ss + 128 + cl * 4);
        sc0 = s4.x; sc1 = s4.y; sc2 = s4.z; sc3 = s4.w;
        sh0 = h4.x; sh1 = h4.y; sh2 = h4.z; sh3 = h4.w;
    }
    int beg = row_start[wid], end = row_start[wid + 1];
    int n = end - beg;
    float a0 = 0.f, a1 = 0.f, a2 = 0.f, a3 = 0.f;
#define ACCUM(vv)                                                                   \
    {                                                                               \
        float t0 = __uint_as_float((vv).x << 16);                                   \
        float t1 = __uint_as_float((vv).x & 0xFFFF0000u);                           \
        float t2 = __uint_as_float((vv).y << 16);                                   \
        float t3 = __uint_as_float((vv).y & 0xFFFF0000u);                           \
        if (AFF) {                                                                  \
            t0 = fmaxf(t0 * sc0 + sh0, 0.f); t1 = fmaxf(t1 * sc1 + sh1, 0.f);       \
            t2 = fmaxf(t2 * sc2 + sh2, 0.f); t3 = fmaxf(t3 * sc3 + sh3, 0.f);       \
        }                                                                           \
        a0 += t0; a1 += t1; a2 += t2; a3 += t3;                                     \
    }
    for (int base = 0; base < n; base += 64) {
        int rem = n - base;
        int idx = beg + base + (lane < rem ? lane : 0);
        int sv = ssrc[idx];
        int m = rem < 64 ? rem : 64;
        int j = 0;
        for (; j + 4 <= m; j += 4) {
            int sA = __shfl(sv, j + half);
            int sB = __shfl(sv, j + 2 + half);
            uint2 vA = *reinterpret_cast<const uint2*>(
                reinterpret_cast<const u32*>(Hh + (size_t)sA * DIM) + cl * 2);
            uint2 vB = *reinterpret_cast<const uint2*>(
                reinterpret_cast<const u32*>(Hh + (size_t)sB * DIM) + cl * 2);
            ACCUM(vA); ACCUM(vB);
        }
        for (; j < m; j += 2) {
            if (j + half < m) {
                int s0 = __shfl(sv, j + half);
                uint2 v = *reinterpret_cast<const uint2*>(
                    reinterpret_cast<const u32*>(Hh + (size_t)s0 * DIM) + cl * 2);
                ACCUM(v);
            }
        }
    }
#undef ACCUM
    a0 += __shfl_down(a0, 32);
    a1 += __shfl_down(a1, 32);
    a2 += __shfl_down(a2, 32);
    a3 += __shfl_down(a3, 32);
    if (half == 0) {
        float sc = inv_deg[wid];
        a0 *= sc; a1 *= sc; a2 *= sc; a3 *= sc;
        u16 h0 = f2bf(a0), h1 = f2bf(a1), h2 = f2bf(a2), h3 = f2bf(a3);
        u16 l0 = f2bf(a0 - bf2f(h0)), l1 = f2bf(a1 - bf2f(h1));
        u16 l2 = f2bf(a2 - bf2f(h2)), l3 = f2bf(a3 - bf2f(h3));
        uint2 hv = make_uint2((u32)h0 | ((u32)h1 << 16), (u32)h2 | ((u32)h3 << 16));
        uint2 lv = make_uint2((u32)l0 | ((u32)l1 << 16), (u32)l2 | ((u32)l3 << 16));
        *reinterpret_cast<uint2*>(Ah + (size_t)wid * DIM + cl * 4) = hv;
        *reinterpret_cast<uint2*>(Al + (size_t)wid * DIM + cl * 4) = lv;
    }
}

// in-register: v = relu(affine(hi+lo)); re-split
__device__ __forceinline__ void affine_split(bf8_t& h, bf8_t& l,
                                             const float* __restrict__ ss, int k0) {
#pragma unroll
    for (int j = 0; j < 8; ++j) {
        float v = bf2f((u16)h[j]) + bf2f((u16)l[j]);
        v = fmaxf(v * ss[k0 + j] + ss[128 + k0 + j], 0.f);
        u16 hh = f2bf(v);
        h[j] = (short)hh;
        l[j] = (short)f2bf(v - bf2f(hh));
    }
}

// ---------------- fused conv GEMM: W register-resident, K-outer, A ping-pong ----
// wave = 64 rows x 32 cols; block = 4 waves = 64x128 tile; grid NGB=1563.
// W frags (hi+lo, full K=256) live in 128 VGPRs -> zero W traffic in K-loop;
// K-loop streams A coalesced with 1-ahead double buffer.
template <bool RELU, bool STATS, bool AFF2>
__global__ __launch_bounds__(256, 2) void k_gemm(
    const u16* __restrict__ A1h, const u16* __restrict__ A1l,
    const u16* __restrict__ A2h, const u16* __restrict__ A2l,
    const u16* __restrict__ Wth, const u16* __restrict__ Wtl,
    const float* __restrict__ bias, const float* __restrict__ ss,
    u16* __restrict__ Oh, u16* __restrict__ Ol,
    float* __restrict__ partials) {
    __shared__ float cs[128], cq[128];
    int t = threadIdx.x;
    int w = t >> 6, l = t & 63;
    int rl = l & 15, kg = l >> 4;
    int col0 = w * 32;
    int rbase = blockIdx.x * 64;
    int rc0 = min(rbase + rl, NN - 1);
    int rc1 = min(rbase + 16 + rl, NN - 1);
    int rc2 = min(rbase + 32 + rl, NN - 1);
    int rc3 = min(rbase + 48 + rl, NN - 1);

    // ---- W fragments into registers (once per wave) ----
    bf8_t wh[2][8], wlo[2][8];
#pragma unroll
    for (int cf = 0; cf < 2; ++cf) {
        const u16* pw = Wth + (size_t)(col0 + cf * 16 + rl) * 256 + kg * 8;
        const u16* pl = Wtl + (size_t)(col0 + cf * 16 + rl) * 256 + kg * 8;
#pragma unroll
        for (int kc = 0; kc < 8; ++kc) {
            wh[cf][kc] = *reinterpret_cast<const bf8_t*>(pw + kc * 32);
            wlo[cf][kc] = *reinterpret_cast<const bf8_t*>(pl + kc * 32);
        }
    }

    f4_t acc[4][2];
#pragma unroll
    for (int i = 0; i < 4; ++i)
#pragma unroll
        for (int j = 0; j < 2; ++j) acc[i][j] = (f4_t){0.f, 0.f, 0.f, 0.f};

    bf8_t aH[4], aL[4], bH[4], bL[4];

#define LOADK(kc, H, L)                                                          \
    {                                                                            \
        const u16* _bh = ((kc) < 4) ? A1h : A2h;                                 \
        const u16* _bl = ((kc) < 4) ? A1l : A2l;                                 \
        int _ko = ((kc) & 3) * 32 + kg * 8;                                      \
        H[0] = *reinterpret_cast<const bf8_t*>(_bh + (size_t)rc0 * DIM + _ko);   \
        L[0] = *reinterpret_cast<const bf8_t*>(_bl + (size_t)rc0 * DIM + _ko);   \
        H[1] = *reinterpret_cast<const bf8_t*>(_bh + (size_t)rc1 * DIM + _ko);   \
        L[1] = *reinterpret_cast<const bf8_t*>(_bl + (size_t)rc1 * DIM + _ko);   \
        H[2] = *reinterpret_cast<const bf8_t*>(_bh + (size_t)rc2 * DIM + _ko);   \
        L[2] = *reinterpret_cast<const bf8_t*>(_bl + (size_t)rc2 * DIM + _ko);   \
        H[3] = *reinterpret_cast<const bf8_t*>(_bh + (size_t)rc3 * DIM + _ko);   \
        L[3] = *reinterpret_cast<const bf8_t*>(_bl + (size_t)rc3 * DIM + _ko);   \
    }

#define COMPK(kc, H, L)                                                          \
    {                                                                            \
        if (AFF2 && (kc) >= 4) {                                                 \
            int _k0 = ((kc) - 4) * 32 + kg * 8;                                  \
            affine_split(H[0], L[0], ss, _k0);                                   \
            affine_split(H[1], L[1], ss, _k0);                                   \
            affine_split(H[2], L[2], ss, _k0);                                   \
            affine_split(H[3], L[3], ss, _k0);                                   \
        }                                                                        \
        _Pragma("unroll")                                                        \
        for (int _rf = 0; _rf < 4; ++_rf) {                                      \
            _Pragma("unroll")                                                    \
            for (int _cf = 0; _cf < 2; ++_cf) {                                  \
                acc[_rf][_cf] = MFMA(H[_rf], wh[_cf][(kc)], acc[_rf][_cf]);      \
                acc[_rf][_cf] = MFMA(H[_rf], wlo[_cf][(kc)], acc[_rf][_cf]);     \
                acc[_rf][_cf] = MFMA(L[_rf], wh[_cf][(kc)], acc[_rf][_cf]);      \
            }                                                                    \
        }                                                                        \
    }

    LOADK(0, aH, aL)
    LOADK(1, bH, bL) COMPK(0, aH, aL)
    LOADK(2, aH, aL) COMPK(1, bH, bL)
    LOADK(3, bH, bL) COMPK(2, aH, aL)
    LOADK(4, aH, aL) COMPK(3, bH, bL)
    LOADK(5, bH, bL) COMPK(4, aH, aL)
    LOADK(6, aH, aL) COMPK(5, bH, bL)
    LOADK(7, bH, bL) COMPK(6, aH, aL)
    COMPK(7, bH, bL)
#undef LOADK
#undef COMPK

    // ---- epilogue: D layout col=lane&15, row=(lane>>4)*4+i [verified m89] ----
    float bv0 = bias[col0 + rl];
    float bv1 = bias[col0 + 16 + rl];
    float s0 = 0.f, q0 = 0.f, s1 = 0.f, q1 = 0.f;
#pragma unroll
    for (int rf = 0; rf < 4; ++rf) {
#pragma unroll
        for (int i = 0; i < 4; ++i) {
            int row = rbase + rf * 16 + kg * 4 + i;
            if (row < NN) {
                float v = acc[rf][0][i] + bv0;
                if (RELU) v = fmaxf(v, 0.f);
                u16 hi = f2bf(v);
                Oh[(size_t)row * DIM + col0 + rl] = hi;
                Ol[(size_t)row * DIM + col0 + rl] = f2bf(v - bf2f(hi));
                if (STATS) { s0 += v; q0 += v * v; }
                float v1 = acc[rf][1][i] + bv1;
                if (RELU) v1 = fmaxf(v1, 0.f);
                u16 hi1 = f2bf(v1);
                Oh[(size_t)row * DIM + col0 + 16 + rl] = hi1;
                Ol[(size_t)row * DIM + col0 + 16 + rl] = f2bf(v1 - bf2f(hi1));
                if (STATS) { s1 += v1; q1 += v1 * v1; }
            }
        }
    }
    if (STATS) {
        s0 += __shfl_xor(s0, 16); s0 += __shfl_xor(s0, 32);
        q0 += __shfl_xor(q0, 16); q0 += __shfl_xor(q0, 32);
        s1 += __shfl_xor(s1, 16); s1 += __shfl_xor(s1, 32);
        q1 += __shfl_xor(q1, 16); q1 += __shfl_xor(q1, 32);
        if (l < 16) {  // each wave owns its 32 cols exclusively -> plain stores
            cs[col0 + rl] = s0; cq[col0 + rl] = q0;
            cs[col0 + 16 + rl] = s1; cq[col0 + 16 + rl] = q1;
        }
        __syncthreads();
        partials[(size_t)blockIdx.x * 256 + t] = (t < 128) ? cs[t] : cq[t - 128];
    }
}

// ---------------- BN: two-stage parallel reduce -> scale/shift ----------------
__global__ void k_bn_r1(const float* __restrict__ partials, float* __restrict__ colpart) {
    int t = threadIdx.x;
    int b = blockIdx.x;  // 32 blocks
    int b0 = b * 49, b1 = min(b0 + 49, NGB);
    float s = 0.f;
    for (int i = b0; i < b1; ++i) s += partials[i * 256 + t];
    colpart[b * 256 + t] = s;
}

__global__ void k_bn_r2(const float* __restrict__ colpart, const float* __restrict__ gamma,
                        const float* __restrict__ beta, float* __restrict__ scaleshift) {
    __shared__ float sm[256];
    int t = threadIdx.x;
    float s = 0.f;
#pragma unroll
    for (int b = 0; b < 32; ++b) s += colpart[b * 256 + t];
    sm[t] = s;
    __syncthreads();
    if (t < 128) {
        float mu = sm[t] * (1.0f / NN);
        float var = sm[t + 128] * (1.0f / NN) - mu * mu;
        float sc = rsqrtf(var + EPSBN) * gamma[t];
        scaleshift[t] = sc;
        scaleshift[t + 128] = beta[t] - mu * sc;
    }
}

// ---------------- pooling: hi-only + fused BN+relu ----------------
__global__ void k_pool(const u16* __restrict__ Hh, const int* __restrict__ gs,
                       const float* __restrict__ ss,
                       float* __restrict__ pSum, float* __restrict__ pMax) {
    int g = blockIdx.x >> 3, slice = blockIdx.x & 7;
    int s0 = gs[g], s1 = gs[g + 1];
    int len = s1 - s0;
    int chunk = (len + 7) >> 3;
    int r0 = s0 + slice * chunk;
    int r1 = min(r0 + chunk, s1);
    int t = threadIdx.x;
    int c2 = (t & 63) * 2, half = t >> 6;
    float sc0 = ss[c2], sc1 = ss[c2 + 1];
    float sh0 = ss[128 + c2], sh1 = ss[128 + c2 + 1];
    float sa = 0.f, sb = 0.f, ma = 0.f, mb = 0.f;
    for (int r = r0 + half; r < r1; r += 4) {
        u32 h2 = *reinterpret_cast<const u32*>(Hh + r * DIM + c2);
        float v0 = fmaxf(__uint_as_float(h2 << 16) * sc0 + sh0, 0.f);
        float v1 = fmaxf(__uint_as_float(h2 & 0xFFFF0000u) * sc1 + sh1, 0.f);
        sa += v0; sb += v1;
        ma = fmaxf(ma, v0); mb = fmaxf(mb, v1);
    }
    __shared__ float ls[4][128], lm[4][128];
    ls[half][c2] = sa; ls[half][c2 + 1] = sb;
    lm[half][c2] = ma; lm[half][c2 + 1] = mb;
    __syncthreads();
    if (t < 128) {
        float s = ls[0][t] + ls[1][t] + ls[2][t] + ls[3][t];
        float m = fmaxf(fmaxf(lm[0][t], lm[1][t]), fmaxf(lm[2][t], lm[3][t]));
        atomicAdd(&pSum[g * DIM + t], s);
        atomicMax((int*)&pMax[g * DIM + t], __float_as_int(m));  // values >= 0, init 0
    }
}

// ---------------- classifier MLP: one block per graph ----------------
__global__ void k_mlp(const float* __restrict__ pSum, const float* __restrict__ pMax,
                      const int* __restrict__ gs,
                      const float* __restrict__ W1, const float* __restrict__ b1,
                      const float* __restrict__ W2, const float* __restrict__ b2,
                      const float* __restrict__ W3, const float* __restrict__ b3,
                      float* __restrict__ out) {
    __shared__ float g[256], y1[128], y2[64];
    int gi = blockIdx.x;
    int t = threadIdx.x;  // 128 threads
    int cnt = gs[gi + 1] - gs[gi];
    float inv = 1.0f / fmaxf((float)cnt, 1.0f);
    g[t] = pSum[gi * DIM + t] * inv;
    g[128 + t] = pMax[gi * DIM + t];
    __syncthreads();
    float a = b1[t];
    for (int k = 0; k < 256; k++) a += g[k] * W1[k * 128 + t];
    y1[t] = fmaxf(a, 0.f);
    __syncthreads();
    if (t < 64) {
        float a2 = b2[t];
        for (int k = 0; k < 128; k++) a2 += y1[k] * W2[k * 64 + t];
        y2[t] = fmaxf(a2, 0.f);
    }
    __syncthreads();
    if (t < 64) {
        float p = y2[t] * W3[t];
#pragma unroll
        for (int off = 32; off; off >>= 1) p += __shfl_down(p, off);
        if (t == 0) out[gi] = p + b3[0];
    }
}

extern "C" void kernel_launch(void* const* d_in, const int* in_sizes, int n_in,
                              void* d_out, int out_size, void* d_ws, size_t ws_size,
                              hipStream_t stream) {
    const float* x     = (const float*)d_in[0];
    const int*   ei    = (const int*)d_in[1];
    const int*   batch = (const int*)d_in[2];
    const float* Wl    = (const float*)d_in[3];
    const float* bl    = (const float*)d_in[4];
    const float* Wr    = (const float*)d_in[5];
    const float* gamma = (const float*)d_in[6];
    const float* beta  = (const float*)d_in[7];
    const float* W1    = (const float*)d_in[8];
    const float* b1    = (const float*)d_in[9];
    const float* W2    = (const float*)d_in[10];
    const float* b2    = (const float*)d_in[11];
    const float* W3    = (const float*)d_in[12];
    const float* b3    = (const float*)d_in[13];
    float* out = (float*)d_out;

    char* p = (char*)d_ws;
    size_t off = 0;
    auto alloc = [&](size_t bytes) -> void* {
        void* r = p + off;
        off += (bytes + 255) & ~(size_t)255;
        return r;
    };
    const size_t HB = (size_t)NN * DIM * 2;
    u16* Xh   = (u16*)alloc(HB);   // block input / conv2 output (pre-BN), ping-pong
    u16* Xl   = (u16*)alloc(HB);
    u16* hAh  = (u16*)alloc(HB);
    u16* hAl  = (u16*)alloc(HB);
    u16* aggh = (u16*)alloc(HB);   // also aliases `binned` during CSR build
    u16* aggl = (u16*)alloc(HB);
    int*   ssrc      = (int*)alloc((size_t)NE * 4);
    u16*   Wth       = (u16*)alloc((size_t)8 * 128 * 256 * 2);
    u16*   Wtl       = (u16*)alloc((size_t)8 * 128 * 256 * 2);
    float* partials  = (float*)alloc((size_t)NGB * 256 * 4);
    float* colpart   = (float*)alloc(32 * 256 * 4);
    int*   deg       = (int*)alloc(NN * 4);
    float* inv_deg   = (float*)alloc(NN * 4);
    int*   row_start = (int*)alloc((NN + 1) * 4);
    int*   cursor    = (int*)alloc(NN * 4);
    int*   bsum      = (int*)alloc(512 * 4);
    int*   gs        = (int*)alloc((NG + 1) * 4);
    int*   blkcnt    = (int*)alloc((size_t)NBINBLK * 8 * 4);
    int*   blkoff    = (int*)alloc((size_t)NBINBLK * 8 * 4);
    int*   wtotal    = (int*)alloc(8 * 4);
    int*   binStart  = (int*)alloc(9 * 4);
    float* ssb       = (float*)alloc(4 * 256 * 4);   // per-block scale/shift
    float* pSum      = (float*)alloc(NG * DIM * 4);
    float* pMax      = (float*)alloc(NG * DIM * 4);
    int2*  binned    = (int2*)aggh;  // 12.8MB, dead before first k_aggregate write

    const int nbN = (NN + 255) / 256;
    const int nbQ = NN * DIM / 4 / 256;  // 12500
    const int aggGrid = (NN + 3) / 4;

    // ---- CSR build (XCD-partitioned) ----
    hipMemsetAsync(deg, 0, NN * 4, stream);
    k_bin_cnt<<<NBINBLK, 256, 0, stream>>>(ei, blkcnt);
    k_bin_scan<<<8, 256, 0, stream>>>(blkcnt, blkoff, wtotal);
    k_bin_start<<<1, 64, 0, stream>>>(wtotal, binStart);
    k_bin_place<<<NBINBLK, 256, 0, stream>>>(ei, blkoff, binStart, binned);
    k_deg2<<<8 * DSL, 256, 0, stream>>>(binned, binStart, deg);
    k_scan1<<<nbN, 256, 0, stream>>>(deg, row_start, bsum, inv_deg);
    k_scan2<<<1, 512, 0, stream>>>(bsum, nbN);
    k_scan3<<<nbN, 256, 0, stream>>>(row_start, bsum, cursor);
    k_scatter<<<8 * DSL, 256, 0, stream>>>(binned, binStart, cursor, ssrc);
    k_bounds<<<1, 128, 0, stream>>>(batch, gs);

    // ---- input + weight prep ----
    k_split_x<<<nbQ, 256, 0, stream>>>(x, Xh, Xl);
    k_prep_w<<<8 * 128 * 256 / 256, 256, 0, stream>>>(Wl, Wr, Wth, Wtl);

    for (int b = 0; b < 4; b++) {
        int c0 = 2 * b, c1 = 2 * b + 1;
        const u16* W0h = Wth + (size_t)c0 * 128 * 256;
        const u16* W0l = Wtl + (size_t)c0 * 128 * 256;
        const u16* W1h = Wth + (size_t)c1 * 128 * 256;
        const u16* W1l = Wtl + (size_t)c1 * 128 * 256;
        const float* ssPrev = ssb + (size_t)(b > 0 ? b - 1 : 0) * 256;
        // agg1 + conv1 (input transform = relu∘affine for b>0, identity for b=0)
        if (b == 0) {
            k_aggregate<0><<<aggGrid, 256, 0, stream>>>(Xh, row_start, ssrc, inv_deg,
                                                        ssPrev, aggh, aggl);
            k_gemm<true, false, false><<<NGB, 256, 0, stream>>>(
                aggh, aggl, Xh, Xl, W0h, W0l, bl + c0 * DIM, ssPrev, hAh, hAl, partials);
        } else {
            k_aggregate<1><<<aggGrid, 256, 0, stream>>>(Xh, row_start, ssrc, inv_deg,
                                                        ssPrev, aggh, aggl);
            k_gemm<true, false, true><<<NGB, 256, 0, stream>>>(
                aggh, aggl, Xh, Xl, W0h, W0l, bl + c0 * DIM, ssPrev, hAh, hAl, partials);
        }
        // agg2 + conv2 (+stats); output pre-BN into Xh/Xl
        k_aggregate<0><<<aggGrid, 256, 0, stream>>>(hAh, row_start, ssrc, inv_deg,
                                                    ssPrev, aggh, aggl);
        k_gemm<false, true, false><<<NGB, 256, 0, stream>>>(
            aggh, aggl, hAh, hAl, W1h, W1l, bl + c1 * DIM, ssPrev, Xh, Xl, partials);
        k_bn_r1<<<32, 256, 0, stream>>>(partials, colpart);
        k_bn_r2<<<1, 256, 0, stream>>>(colpart, gamma + b * DIM, beta + b * DIM,
                                       ssb + (size_t)b * 256);
    }

    // ---- pooling (fused BN+relu) + classifier ----
    hipMemsetAsync(pSum, 0, NG * DIM * 4, stream);
    hipMemsetAsync(pMax, 0, NG * DIM * 4, stream);
    k_pool<<<NG * 8, 256, 0, stream>>>(Xh, gs, ssb + 3 * 256, pSum, pMax);
    k_mlp<<<NG, 128, 0, stream>>>(pSum, pMax, gs, W1, b1, W2, b2, W3, b3, out);
}

// Round 7
// 1397.929 us; speedup vs baseline: 2.6831x; 1.1773x over previous
//
#include <hip/hip_runtime.h>
#include <hip/hip_bf16.h>
#include <math.h>

#define NN 100000
#define NE 1600000
#define DIM 128
#define NG 64
#define EPSBN 1e-5f
#define NGB 1563        // (NN+63)/64 gemm tiles
#define SORT_WIN 12500  // NN/8 dst-window
#define NBINBLK 6250    // NE/256
#define DSL 64          // slices per window for deg2/scatter

typedef unsigned int u32;
typedef unsigned short u16;
typedef __attribute__((ext_vector_type(8))) short bf8_t;   // 8 x bf16
typedef __attribute__((ext_vector_type(4))) float f4_t;    // 4 x f32
typedef __attribute__((ext_vector_type(4))) unsigned short u16x4;
#define MFMA(a, b, c) __builtin_amdgcn_mfma_f32_16x16x32_bf16((a), (b), (c), 0, 0, 0)

__device__ __forceinline__ u16 f2bf(float f) {
    u32 u = __float_as_uint(f);
    u32 r = u + 0x7FFFu + ((u >> 16) & 1u);   // round-to-nearest-even
    return (u16)(r >> 16);
}
__device__ __forceinline__ float bf2f(u16 h) { return __uint_as_float(((u32)h) << 16); }

// ============ CSR build, XCD-partitioned ============
__global__ void k_bin_cnt(const int* __restrict__ ei, int* __restrict__ blkcnt) {
    __shared__ int c[8];
    int t = threadIdx.x;
    if (t < 8) c[t] = 0;
    __syncthreads();
    int e = blockIdx.x * 256 + t;
    int d = ei[NE + e];
    atomicAdd(&c[d / SORT_WIN], 1);
    __syncthreads();
    if (t < 8) blkcnt[blockIdx.x * 8 + t] = c[t];
}

__global__ void k_bin_scan(const int* __restrict__ blkcnt, int* __restrict__ blkoff,
                           int* __restrict__ wtotal) {
    __shared__ int ps[256];
    int w = blockIdx.x, t = threadIdx.x;
    const int PER = (NBINBLK + 255) / 256;  // 25
    int s = 0;
    for (int i = 0; i < PER; ++i) {
        int b = t * PER + i;
        if (b < NBINBLK) s += blkcnt[b * 8 + w];
    }
    ps[t] = s;
    for (int off = 1; off < 256; off <<= 1) {
        __syncthreads();
        int x = (t >= off) ? ps[t - off] : 0;
        __syncthreads();
        ps[t] += x;
    }
    __syncthreads();
    int run = (t ? ps[t - 1] : 0);
    for (int i = 0; i < PER; ++i) {
        int b = t * PER + i;
        if (b < NBINBLK) { blkoff[b * 8 + w] = run; run += blkcnt[b * 8 + w]; }
    }
    if (t == 255) wtotal[w] = ps[255];
}

__global__ void k_bin_start(const int* __restrict__ wtotal, int* __restrict__ binStart) {
    if (threadIdx.x == 0) {
        int a = 0;
        for (int w = 0; w < 8; ++w) { binStart[w] = a; a += wtotal[w]; }
        binStart[8] = a;
    }
}

__global__ void k_bin_place(const int* __restrict__ ei, const int* __restrict__ blkoff,
                            const int* __restrict__ binStart, int2* __restrict__ binned) {
    __shared__ int base[8];
    int t = threadIdx.x;
    if (t < 8) base[t] = binStart[t] + blkoff[blockIdx.x * 8 + t];
    __syncthreads();
    int e = blockIdx.x * 256 + t;
    int s = ei[e], d = ei[NE + e];
    int pos = atomicAdd(&base[d / SORT_WIN], 1);
    binned[pos] = make_int2(s, d);
}

__global__ void k_deg2(const int2* __restrict__ binned, const int* __restrict__ binStart,
                       int* __restrict__ deg) {
    int w = blockIdx.x & 7, sl = blockIdx.x >> 3;
    int b0 = binStart[w], b1 = binStart[w + 1];
    int chunk = (b1 - b0 + DSL - 1) / DSL;
    int r0 = b0 + sl * chunk, r1 = min(r0 + chunk, b1);
    for (int i = r0 + threadIdx.x; i < r1; i += 256)
        atomicAdd(&deg[binned[i].y], 1);
}

__global__ void k_scatter(const int2* __restrict__ binned, const int* __restrict__ binStart,
                          int* __restrict__ cursor, int* __restrict__ sorted_src) {
    int w = blockIdx.x & 7, sl = blockIdx.x >> 3;
    int b0 = binStart[w], b1 = binStart[w + 1];
    int chunk = (b1 - b0 + DSL - 1) / DSL;
    int r0 = b0 + sl * chunk, r1 = min(r0 + chunk, b1);
    for (int i = r0 + threadIdx.x; i < r1; i += 256) {
        int2 e = binned[i];
        int pos = atomicAdd(&cursor[e.y], 1);
        sorted_src[pos] = e.x;
    }
}

#define SCAN_B 256
__global__ void k_scan1(const int* __restrict__ deg, int* __restrict__ row_start,
                        int* __restrict__ bsum, float* __restrict__ inv_deg) {
    __shared__ int s[SCAN_B];
    int t = threadIdx.x;
    int i = blockIdx.x * SCAN_B + t;
    int v = (i < NN) ? deg[i] : 0;
    if (i < NN) inv_deg[i] = 1.0f / (float)(v > 1 ? v : 1);
    s[t] = v;
    for (int off = 1; off < SCAN_B; off <<= 1) {
        __syncthreads();
        int x = (t >= off) ? s[t - off] : 0;
        __syncthreads();
        s[t] += x;
    }
    if (i < NN) row_start[i + 1] = s[t];
    if (t == SCAN_B - 1) bsum[blockIdx.x] = s[t];
}

__global__ void k_scan2(int* __restrict__ bsum, int nb) {
    __shared__ int s[512];
    int t = threadIdx.x;
    int v = (t < nb) ? bsum[t] : 0;
    s[t] = v;
    for (int off = 1; off < 512; off <<= 1) {
        __syncthreads();
        int x = (t >= off) ? s[t - off] : 0;
        __syncthreads();
        s[t] += x;
    }
    if (t < nb) bsum[t] = s[t] - v;
}

__global__ void k_scan3(int* __restrict__ row_start, const int* __restrict__ bsum,
                        int* __restrict__ cursor) {
    int i = blockIdx.x * blockDim.x + threadIdx.x;
    if (i < NN) {
        int v = row_start[i + 1] + bsum[i / SCAN_B];
        row_start[i + 1] = v;
        if (i + 1 < NN) cursor[i + 1] = v;
    }
    if (i == 0) { row_start[0] = 0; cursor[0] = 0; }
}

__global__ void k_bounds(const int* __restrict__ batch, int* __restrict__ gs) {
    int g = threadIdx.x;
    if (g > NG) return;
    int lo = 0, hi = NN;
    while (lo < hi) {
        int mid = (lo + hi) >> 1;
        if (batch[mid] < g) lo = mid + 1; else hi = mid;
    }
    gs[g] = lo;
}

// ---------------- fp32 x -> split bf16 (hi, lo) ----------------
__global__ void k_split_x(const float* __restrict__ x, u16* __restrict__ Xh,
                          u16* __restrict__ Xl) {
    int idx = blockIdx.x * 256 + threadIdx.x;
    int base = idx * 4;
    float4 v = *reinterpret_cast<const float4*>(&x[base]);
    u16x4 hi, lo;
    float vv[4] = {v.x, v.y, v.z, v.w};
#pragma unroll
    for (int j = 0; j < 4; j++) {
        u16 h = f2bf(vv[j]);
        hi[j] = h;
        lo[j] = f2bf(vv[j] - bf2f(h));
    }
    *reinterpret_cast<u16x4*>(&Xh[base]) = hi;
    *reinterpret_cast<u16x4*>(&Xl[base]) = lo;
}

// ---------------- weight prep: transpose+stack+split ----------------
__global__ void k_prep_w(const float* __restrict__ Wl, const float* __restrict__ Wr,
                         u16* __restrict__ Wth, u16* __restrict__ Wtl) {
    int idx = blockIdx.x * 256 + threadIdx.x;  // 8*128*256
    int k = idx & 255;
    int col = (idx >> 8) & 127;
    int c = idx >> 15;
    float v = (k < 128) ? Wl[(c * 128 + k) * 128 + col] : Wr[(c * 128 + (k - 128)) * 128 + col];
    u16 h = f2bf(v);
    Wth[idx] = h;
    Wtl[idx] = f2bf(v - bf2f(h));
}

// ---------------- mean aggregation: hi-only gather; optional fused BN+relu -----
template <int AFF>
__global__ void k_aggregate(const u16* __restrict__ Hh,
                            const int* __restrict__ row_start, const int* __restrict__ ssrc,
                            const float* __restrict__ inv_deg, const float* __restrict__ ss,
                            u16* __restrict__ Ah, u16* __restrict__ Al) {
    int wid = blockIdx.x * 4 + (threadIdx.x >> 6);
    int lane = threadIdx.x & 63;
    int half = lane >> 5;
    int cl = lane & 31;     // cols [cl*4, cl*4+4)
    if (wid >= NN) return;
    float sc0 = 0.f, sc1 = 0.f, sc2 = 0.f, sc3 = 0.f;
    float sh0 = 0.f, sh1 = 0.f, sh2 = 0.f, sh3 = 0.f;
    if (AFF) {
        float4 s4 = *reinterpret_cast<const float4*>(ss + cl * 4);
        float4 h4 = *reinterpret_cast<const float4*>(ss + 128 + cl * 4);
        sc0 = s4.x; sc1 = s4.y; sc2 = s4.z; sc3 = s4.w;
        sh0 = h4.x; sh1 = h4.y; sh2 = h4.z; sh3 = h4.w;
    }
    int beg = row_start[wid], end = row_start[wid + 1];
    int n = end - beg;
    float a0 = 0.f, a1 = 0.f, a2 = 0.f, a3 = 0.f;
#define ACCUM(vv)                                                                   \
    {                                                                               \
        float t0 = __uint_as_float((vv).x << 16);                                   \
        float t1 = __uint_as_float((vv).x & 0xFFFF0000u);                           \
        float t2 = __uint_as_float((vv).y << 16);                                   \
        float t3 = __uint_as_float((vv).y & 0xFFFF0000u);                           \
        if (AFF) {                                                                  \
            t0 = fmaxf(t0 * sc0 + sh0, 0.f); t1 = fmaxf(t1 * sc1 + sh1, 0.f);       \
            t2 = fmaxf(t2 * sc2 + sh2, 0.f); t3 = fmaxf(t3 * sc3 + sh3, 0.f);       \
        }                                                                           \
        a0 += t0; a1 += t1; a2 += t2; a3 += t3;                                     \
    }
    for (int base = 0; base < n; base += 64) {
        int rem = n - base;
        int idx = beg + base + (lane < rem ? lane : 0);
        int sv = ssrc[idx];
        int m = rem < 64 ? rem : 64;
        int j = 0;
        for (; j + 4 <= m; j += 4) {
            int sA = __shfl(sv, j + half);
            int sB = __shfl(sv, j + 2 + half);
            uint2 vA = *reinterpret_cast<const uint2*>(
                reinterpret_cast<const u32*>(Hh + (size_t)sA * DIM) + cl * 2);
            uint2 vB = *reinterpret_cast<const uint2*>(
                reinterpret_cast<const u32*>(Hh + (size_t)sB * DIM) + cl * 2);
            ACCUM(vA); ACCUM(vB);
        }
        for (; j < m; j += 2) {
            if (j + half < m) {
                int s0 = __shfl(sv, j + half);
                uint2 v = *reinterpret_cast<const uint2*>(
                    reinterpret_cast<const u32*>(Hh + (size_t)s0 * DIM) + cl * 2);
                ACCUM(v);
            }
        }
    }
#undef ACCUM
    a0 += __shfl_down(a0, 32);
    a1 += __shfl_down(a1, 32);
    a2 += __shfl_down(a2, 32);
    a3 += __shfl_down(a3, 32);
    if (half == 0) {
        float sc = inv_deg[wid];
        a0 *= sc; a1 *= sc; a2 *= sc; a3 *= sc;
        u16 h0 = f2bf(a0), h1 = f2bf(a1), h2 = f2bf(a2), h3 = f2bf(a3);
        u16 l0 = f2bf(a0 - bf2f(h0)), l1 = f2bf(a1 - bf2f(h1));
        u16 l2 = f2bf(a2 - bf2f(h2)), l3 = f2bf(a3 - bf2f(h3));
        uint2 hv = make_uint2((u32)h0 | ((u32)h1 << 16), (u32)h2 | ((u32)h3 << 16));
        uint2 lv = make_uint2((u32)l0 | ((u32)l1 << 16), (u32)l2 | ((u32)l3 << 16));
        *reinterpret_cast<uint2*>(Ah + (size_t)wid * DIM + cl * 4) = hv;
        *reinterpret_cast<uint2*>(Al + (size_t)wid * DIM + cl * 4) = lv;
    }
}

// in-register: v = relu(affine(hi+lo)); re-split
__device__ __forceinline__ void affine_split(bf8_t& h, bf8_t& l,
                                             const float* __restrict__ ss, int k0) {
#pragma unroll
    for (int j = 0; j < 8; ++j) {
        float v = bf2f((u16)h[j]) + bf2f((u16)l[j]);
        v = fmaxf(v * ss[k0 + j] + ss[128 + k0 + j], 0.f);
        u16 hh = f2bf(v);
        h[j] = (short)hh;
        l[j] = (short)f2bf(v - bf2f(hh));
    }
}

// ---------------- fused conv GEMM: A staged via global_load_lds ---------------
// block = 4 waves, tile 64 rows x 128 cols; wave = 64 rows x 32 cols.
// A-tiles (A1h/A1l/A2h/A2l, 16KB each) DMA'd to LDS with chunk-XOR swizzle
// (source-side permute + read-side XOR, rule #21); K-loop: ds_read A, direct W.
template <bool RELU, bool STATS, bool AFF2>
__global__ __launch_bounds__(256, 2) void k_gemm(
    const u16* __restrict__ A1h, const u16* __restrict__ A1l,
    const u16* __restrict__ A2h, const u16* __restrict__ A2l,
    const u16* __restrict__ Wth, const u16* __restrict__ Wtl,
    const float* __restrict__ bias, const float* __restrict__ ss,
    u16* __restrict__ Oh, u16* __restrict__ Ol,
    float* __restrict__ partials) {
    __shared__ u16 sA[4][64][128];   // 64KB; chunk c_mem holds data-chunk c_mem^(row&7)
    __shared__ float cs[128], cq[128];
    int t = threadIdx.x;
    int w = t >> 6, l = t & 63;
    int rl = l & 15, kg = l >> 4;
    int col0 = w * 32;
    int rbase = blockIdx.x * 64;

    // ---- stage: 4 regions x 4 global_load_lds per wave (16B/lane each) ----
    const u16* srcs[4] = {A1h, A1l, A2h, A2l};
#pragma unroll
    for (int R = 0; R < 4; ++R) {
#pragma unroll
        for (int i = 0; i < 4; ++i) {
            int slot = i * 256 + w * 64 + l;       // 16B slots, linear in LDS
            int row = slot >> 4, cm = slot & 15;
            int cd = cm ^ (row & 7);               // source-side inverse swizzle
            int rowc = min(rbase + row, NN - 1);
            const u16* g = srcs[R] + (size_t)rowc * DIM + cd * 8;
            u16* lp = &sA[R][0][0] + (size_t)(i * 256 + w * 64) * 8;  // wave-uniform
            __builtin_amdgcn_global_load_lds(
                (const __attribute__((address_space(1))) void*)g,
                (__attribute__((address_space(3))) void*)lp, 16, 0, 0);
        }
    }
    asm volatile("s_waitcnt vmcnt(0)" ::: "memory");
    __syncthreads();

    f4_t acc[4][2];
#pragma unroll
    for (int i = 0; i < 4; ++i)
#pragma unroll
        for (int j = 0; j < 2; ++j) acc[i][j] = (f4_t){0.f, 0.f, 0.f, 0.f};

    // read of data-chunk cd for row r: LDS chunk = cd ^ (r&7)
#define AFRAG(R, kc, rf)                                                            \
    (*reinterpret_cast<const bf8_t*>(                                               \
        &sA[(R)][(rf) * 16 + rl][((((kc) & 3) * 4 + kg) ^ (rl & 7)) * 8]))

#pragma unroll
    for (int kc = 0; kc < 8; ++kc) {
        int Rh = (kc < 4) ? 0 : 2;
        bf8_t wh0 = *reinterpret_cast<const bf8_t*>(
            Wth + (size_t)(col0 + rl) * 256 + kc * 32 + kg * 8);
        bf8_t wl0 = *reinterpret_cast<const bf8_t*>(
            Wtl + (size_t)(col0 + rl) * 256 + kc * 32 + kg * 8);
        bf8_t wh1 = *reinterpret_cast<const bf8_t*>(
            Wth + (size_t)(col0 + 16 + rl) * 256 + kc * 32 + kg * 8);
        bf8_t wl1 = *reinterpret_cast<const bf8_t*>(
            Wtl + (size_t)(col0 + 16 + rl) * 256 + kc * 32 + kg * 8);
#pragma unroll
        for (int rf = 0; rf < 4; ++rf) {
            bf8_t aH = AFRAG(Rh, kc, rf);
            bf8_t aL = AFRAG(Rh + 1, kc, rf);
            if (AFF2 && kc >= 4) {
                int k0 = (kc - 4) * 32 + kg * 8;
                affine_split(aH, aL, ss, k0);
            }
            acc[rf][0] = MFMA(aH, wh0, acc[rf][0]);
            acc[rf][0] = MFMA(aH, wl0, acc[rf][0]);
            acc[rf][0] = MFMA(aL, wh0, acc[rf][0]);
            acc[rf][1] = MFMA(aH, wh1, acc[rf][1]);
            acc[rf][1] = MFMA(aH, wl1, acc[rf][1]);
            acc[rf][1] = MFMA(aL, wh1, acc[rf][1]);
        }
    }
#undef AFRAG

    // ---- epilogue: D layout col=lane&15, row=(lane>>4)*4+i [verified m89] ----
    float bv0 = bias[col0 + rl];
    float bv1 = bias[col0 + 16 + rl];
    float s0 = 0.f, q0 = 0.f, s1 = 0.f, q1 = 0.f;
#pragma unroll
    for (int rf = 0; rf < 4; ++rf) {
#pragma unroll
        for (int i = 0; i < 4; ++i) {
            int row = rbase + rf * 16 + kg * 4 + i;
            if (row < NN) {
                float v = acc[rf][0][i] + bv0;
                if (RELU) v = fmaxf(v, 0.f);
                u16 hi = f2bf(v);
                Oh[(size_t)row * DIM + col0 + rl] = hi;
                Ol[(size_t)row * DIM + col0 + rl] = f2bf(v - bf2f(hi));
                if (STATS) { s0 += v; q0 += v * v; }
                float v1 = acc[rf][1][i] + bv1;
                if (RELU) v1 = fmaxf(v1, 0.f);
                u16 hi1 = f2bf(v1);
                Oh[(size_t)row * DIM + col0 + 16 + rl] = hi1;
                Ol[(size_t)row * DIM + col0 + 16 + rl] = f2bf(v1 - bf2f(hi1));
                if (STATS) { s1 += v1; q1 += v1 * v1; }
            }
        }
    }
    if (STATS) {
        s0 += __shfl_xor(s0, 16); s0 += __shfl_xor(s0, 32);
        q0 += __shfl_xor(q0, 16); q0 += __shfl_xor(q0, 32);
        s1 += __shfl_xor(s1, 16); s1 += __shfl_xor(s1, 32);
        q1 += __shfl_xor(q1, 16); q1 += __shfl_xor(q1, 32);
        if (l < 16) {  // each wave owns its 32 cols exclusively -> plain stores
            cs[col0 + rl] = s0; cq[col0 + rl] = q0;
            cs[col0 + 16 + rl] = s1; cq[col0 + 16 + rl] = q1;
        }
        __syncthreads();
        partials[(size_t)blockIdx.x * 256 + t] = (t < 128) ? cs[t] : cq[t - 128];
    }
}

// ---------------- BN: two-stage parallel reduce -> scale/shift ----------------
__global__ void k_bn_r1(const float* __restrict__ partials, float* __restrict__ colpart) {
    int t = threadIdx.x;
    int b = blockIdx.x;  // 32 blocks
    int b0 = b * 49, b1 = min(b0 + 49, NGB);
    float s = 0.f;
    for (int i = b0; i < b1; ++i) s += partials[i * 256 + t];
    colpart[b * 256 + t] = s;
}

__global__ void k_bn_r2(const float* __restrict__ colpart, const float* __restrict__ gamma,
                        const float* __restrict__ beta, float* __restrict__ scaleshift) {
    __shared__ float sm[256];
    int t = threadIdx.x;
    float s = 0.f;
#pragma unroll
    for (int b = 0; b < 32; ++b) s += colpart[b * 256 + t];
    sm[t] = s;
    __syncthreads();
    if (t < 128) {
        float mu = sm[t] * (1.0f / NN);
        float var = sm[t + 128] * (1.0f / NN) - mu * mu;
        float sc = rsqrtf(var + EPSBN) * gamma[t];
        scaleshift[t] = sc;
        scaleshift[t + 128] = beta[t] - mu * sc;
    }
}

// ---------------- pooling: hi-only + fused BN+relu ----------------
__global__ void k_pool(const u16* __restrict__ Hh, const int* __restrict__ gs,
                       const float* __restrict__ ss,
                       float* __restrict__ pSum, float* __restrict__ pMax) {
    int g = blockIdx.x >> 3, slice = blockIdx.x & 7;
    int s0 = gs[g], s1 = gs[g + 1];
    int len = s1 - s0;
    int chunk = (len + 7) >> 3;
    int r0 = s0 + slice * chunk;
    int r1 = min(r0 + chunk, s1);
    int t = threadIdx.x;
    int c2 = (t & 63) * 2, half = t >> 6;
    float sc0 = ss[c2], sc1 = ss[c2 + 1];
    float sh0 = ss[128 + c2], sh1 = ss[128 + c2 + 1];
    float sa = 0.f, sb = 0.f, ma = 0.f, mb = 0.f;
    for (int r = r0 + half; r < r1; r += 4) {
        u32 h2 = *reinterpret_cast<const u32*>(Hh + r * DIM + c2);
        float v0 = fmaxf(__uint_as_float(h2 << 16) * sc0 + sh0, 0.f);
        float v1 = fmaxf(__uint_as_float(h2 & 0xFFFF0000u) * sc1 + sh1, 0.f);
        sa += v0; sb += v1;
        ma = fmaxf(ma, v0); mb = fmaxf(mb, v1);
    }
    __shared__ float ls[4][128], lm[4][128];
    ls[half][c2] = sa; ls[half][c2 + 1] = sb;
    lm[half][c2] = ma; lm[half][c2 + 1] = mb;
    __syncthreads();
    if (t < 128) {
        float s = ls[0][t] + ls[1][t] + ls[2][t] + ls[3][t];
        float m = fmaxf(fmaxf(lm[0][t], lm[1][t]), fmaxf(lm[2][t], lm[3][t]));
        atomicAdd(&pSum[g * DIM + t], s);
        atomicMax((int*)&pMax[g * DIM + t], __float_as_int(m));  // values >= 0, init 0
    }
}

// ---------------- classifier MLP: one block per graph ----------------
__global__ void k_mlp(const float* __restrict__ pSum, const float* __restrict__ pMax,
                      const int* __restrict__ gs,
                      const float* __restrict__ W1, const float* __restrict__ b1,
                      const float* __restrict__ W2, const float* __restrict__ b2,
                      const float* __restrict__ W3, const float* __restrict__ b3,
                      float* __restrict__ out) {
    __shared__ float g[256], y1[128], y2[64];
    int gi = blockIdx.x;
    int t = threadIdx.x;  // 128 threads
    int cnt = gs[gi + 1] - gs[gi];
    float inv = 1.0f / fmaxf((float)cnt, 1.0f);
    g[t] = pSum[gi * DIM + t] * inv;
    g[128 + t] = pMax[gi * DIM + t];
    __syncthreads();
    float a = b1[t];
    for (int k = 0; k < 256; k++) a += g[k] * W1[k * 128 + t];
    y1[t] = fmaxf(a, 0.f);
    __syncthreads();
    if (t < 64) {
        float a2 = b2[t];
        for (int k = 0; k < 128; k++) a2 += y1[k] * W2[k * 64 + t];
        y2[t] = fmaxf(a2, 0.f);
    }
    __syncthreads();
    if (t < 64) {
        float p = y2[t] * W3[t];
#pragma unroll
        for (int off = 32; off; off >>= 1) p += __shfl_down(p, off);
        if (t == 0) out[gi] = p + b3[0];
    }
}

extern "C" void kernel_launch(void* const* d_in, const int* in_sizes, int n_in,
                              void* d_out, int out_size, void* d_ws, size_t ws_size,
                              hipStream_t stream) {
    const float* x     = (const float*)d_in[0];
    const int*   ei    = (const int*)d_in[1];
    const int*   batch = (const int*)d_in[2];
    const float* Wl    = (const float*)d_in[3];
    const float* bl    = (const float*)d_in[4];
    const float* Wr    = (const float*)d_in[5];
    const float* gamma = (const float*)d_in[6];
    const float* beta  = (const float*)d_in[7];
    const float* W1    = (const float*)d_in[8];
    const float* b1    = (const float*)d_in[9];
    const float* W2    = (const float*)d_in[10];
    const float* b2    = (const float*)d_in[11];
    const float* W3    = (const float*)d_in[12];
    const float* b3    = (const float*)d_in[13];
    float* out = (float*)d_out;

    char* p = (char*)d_ws;
    size_t off = 0;
    auto alloc = [&](size_t bytes) -> void* {
        void* r = p + off;
        off += (bytes + 255) & ~(size_t)255;
        return r;
    };
    const size_t HB = (size_t)NN * DIM * 2;
    u16* Xh   = (u16*)alloc(HB);   // block input / conv2 output (pre-BN), ping-pong
    u16* Xl   = (u16*)alloc(HB);
    u16* hAh  = (u16*)alloc(HB);
    u16* hAl  = (u16*)alloc(HB);
    u16* aggh = (u16*)alloc(HB);   // also aliases `binned` during CSR build
    u16* aggl = (u16*)alloc(HB);
    int*   ssrc      = (int*)alloc((size_t)NE * 4);
    u16*   Wth       = (u16*)alloc((size_t)8 * 128 * 256 * 2);
    u16*   Wtl       = (u16*)alloc((size_t)8 * 128 * 256 * 2);
    float* partials  = (float*)alloc((size_t)NGB * 256 * 4);
    float* colpart   = (float*)alloc(32 * 256 * 4);
    int*   deg       = (int*)alloc(NN * 4);
    float* inv_deg   = (float*)alloc(NN * 4);
    int*   row_start = (int*)alloc((NN + 1) * 4);
    int*   cursor    = (int*)alloc(NN * 4);
    int*   bsum      = (int*)alloc(512 * 4);
    int*   gs        = (int*)alloc((NG + 1) * 4);
    int*   blkcnt    = (int*)alloc((size_t)NBINBLK * 8 * 4);
    int*   blkoff    = (int*)alloc((size_t)NBINBLK * 8 * 4);
    int*   wtotal    = (int*)alloc(8 * 4);
    int*   binStart  = (int*)alloc(9 * 4);
    float* ssb       = (float*)alloc(4 * 256 * 4);   // per-block scale/shift
    float* pSum      = (float*)alloc(NG * DIM * 4);
    float* pMax      = (float*)alloc(NG * DIM * 4);
    int2*  binned    = (int2*)aggh;  // 12.8MB, dead before first k_aggregate write

    const int nbN = (NN + 255) / 256;
    const int nbQ = NN * DIM / 4 / 256;  // 12500
    const int aggGrid = (NN + 3) / 4;

    // ---- CSR build (XCD-partitioned) ----
    hipMemsetAsync(deg, 0, NN * 4, stream);
    k_bin_cnt<<<NBINBLK, 256, 0, stream>>>(ei, blkcnt);
    k_bin_scan<<<8, 256, 0, stream>>>(blkcnt, blkoff, wtotal);
    k_bin_start<<<1, 64, 0, stream>>>(wtotal, binStart);
    k_bin_place<<<NBINBLK, 256, 0, stream>>>(ei, blkoff, binStart, binned);
    k_deg2<<<8 * DSL, 256, 0, stream>>>(binned, binStart, deg);
    k_scan1<<<nbN, 256, 0, stream>>>(deg, row_start, bsum, inv_deg);
    k_scan2<<<1, 512, 0, stream>>>(bsum, nbN);
    k_scan3<<<nbN, 256, 0, stream>>>(row_start, bsum, cursor);
    k_scatter<<<8 * DSL, 256, 0, stream>>>(binned, binStart, cursor, ssrc);
    k_bounds<<<1, 128, 0, stream>>>(batch, gs);

    // ---- input + weight prep ----
    k_split_x<<<nbQ, 256, 0, stream>>>(x, Xh, Xl);
    k_prep_w<<<8 * 128 * 256 / 256, 256, 0, stream>>>(Wl, Wr, Wth, Wtl);

    for (int b = 0; b < 4; b++) {
        int c0 = 2 * b, c1 = 2 * b + 1;
        const u16* W0h = Wth + (size_t)c0 * 128 * 256;
        const u16* W0l = Wtl + (size_t)c0 * 128 * 256;
        const u16* W1h = Wth + (size_t)c1 * 128 * 256;
        const u16* W1l = Wtl + (size_t)c1 * 128 * 256;
        const float* ssPrev = ssb + (size_t)(b > 0 ? b - 1 : 0) * 256;
        // agg1 + conv1 (input transform = relu∘affine for b>0, identity for b=0)
        if (b == 0) {
            k_aggregate<0><<<aggGrid, 256, 0, stream>>>(Xh, row_start, ssrc, inv_deg,
                                                        ssPrev, aggh, aggl);
            k_gemm<true, false, false><<<NGB, 256, 0, stream>>>(
                aggh, aggl, Xh, Xl, W0h, W0l, bl + c0 * DIM, ssPrev, hAh, hAl, partials);
        } else {
            k_aggregate<1><<<aggGrid, 256, 0, stream>>>(Xh, row_start, ssrc, inv_deg,
                                                        ssPrev, aggh, aggl);
            k_gemm<true, false, true><<<NGB, 256, 0, stream>>>(
                aggh, aggl, Xh, Xl, W0h, W0l, bl + c0 * DIM, ssPrev, hAh, hAl, partials);
        }
        // agg2 + conv2 (+stats); output pre-BN into Xh/Xl
        k_aggregate<0><<<aggGrid, 256, 0, stream>>>(hAh, row_start, ssrc, inv_deg,
                                                    ssPrev, aggh, aggl);
        k_gemm<false, true, false><<<NGB, 256, 0, stream>>>(
            aggh, aggl, hAh, hAl, W1h, W1l, bl + c1 * DIM, ssPrev, Xh, Xl, partials);
        k_bn_r1<<<32, 256, 0, stream>>>(partials, colpart);
        k_bn_r2<<<1, 256, 0, stream>>>(colpart, gamma + b * DIM, beta + b * DIM,
                                       ssb + (size_t)b * 256);
    }

    // ---- pooling (fused BN+relu) + classifier ----
    hipMemsetAsync(pSum, 0, NG * DIM * 4, stream);
    hipMemsetAsync(pMax, 0, NG * DIM * 4, stream);
    k_pool<<<NG * 8, 256, 0, stream>>>(Xh, gs, ssb + 3 * 256, pSum, pMax);
    k_mlp<<<NG, 128, 0, stream>>>(pSum, pMax, gs, W1, b1, W2, b2, W3, b3, out);
}